// Round 1
// baseline (301.851 us; speedup 1.0000x reference)
//
#include <hip/hip_runtime.h>
#include <hip/hip_bf16.h>
#include <math.h>

typedef _Float16 f16;
typedef __attribute__((ext_vector_type(8))) _Float16 f16x8;
typedef __attribute__((ext_vector_type(4))) float f32x4;

#define M_TOT 8192      // BATCH*SEQ
#define E_DIM 1024
#define F_DIM 4096
#define NQ    16

// ---------------- cast f32 -> f16 for x, W1, Wo (one kernel) ----------------
__global__ __launch_bounds__(256) void cast_kernel(
    const float* __restrict__ x, const float* __restrict__ w1,
    const float* __restrict__ wo, f16* __restrict__ xh,
    f16* __restrict__ w1h, f16* __restrict__ woh)
{
    const size_t NX = (size_t)M_TOT * E_DIM;      // 8388608
    const size_t NW = (size_t)F_DIM * E_DIM;      // 4194304
    size_t i = ((size_t)blockIdx.x * 256 + threadIdx.x) * 8;
    const float* src; f16* dst; size_t off;
    if (i < NX)           { src = x;  dst = xh;  off = i; }
    else if (i < NX + NW) { src = w1; dst = w1h; off = i - NX; }
    else                  { src = wo; dst = woh; off = i - NX - NW; }
    float4 v0 = *reinterpret_cast<const float4*>(src + off);
    float4 v1 = *reinterpret_cast<const float4*>(src + off + 4);
    f16x8 o;
    o[0] = (f16)v0.x; o[1] = (f16)v0.y; o[2] = (f16)v0.z; o[3] = (f16)v0.w;
    o[4] = (f16)v1.x; o[5] = (f16)v1.y; o[6] = (f16)v1.z; o[7] = (f16)v1.w;
    *reinterpret_cast<f16x8*>(dst + off) = o;
}

// ------------- pad kernel: Wq -> [128][4096] f16, W2 -> [4096][32] f16 -------------
__global__ __launch_bounds__(256) void pad_kernel(
    const float* __restrict__ Wq, const float* __restrict__ W2,
    f16* __restrict__ wqp, f16* __restrict__ w2p)
{
    int t = blockIdx.x * 256 + threadIdx.x;   // 0 .. 81920
    if (t < 65536) {
        size_t i = (size_t)t * 8;             // flat into [128][4096]
        int row = (int)(i >> 12);
        f16x8 o;
        if (row < NQ) {
            float4 v0 = *reinterpret_cast<const float4*>(Wq + i);
            float4 v1 = *reinterpret_cast<const float4*>(Wq + i + 4);
            o[0] = (f16)v0.x; o[1] = (f16)v0.y; o[2] = (f16)v0.z; o[3] = (f16)v0.w;
            o[4] = (f16)v1.x; o[5] = (f16)v1.y; o[6] = (f16)v1.z; o[7] = (f16)v1.w;
        } else {
            for (int k = 0; k < 8; ++k) o[k] = (f16)0.f;
        }
        *reinterpret_cast<f16x8*>(wqp + i) = o;
    } else {
        int t2 = t - 65536;
        size_t i = (size_t)t2 * 8;            // flat into [4096][32]
        int row = (int)(i >> 5);
        int col = (int)(i & 31);
        f16x8 o;
        if (col < NQ) {
            float4 v0 = *reinterpret_cast<const float4*>(W2 + (size_t)row * NQ + col);
            float4 v1 = *reinterpret_cast<const float4*>(W2 + (size_t)row * NQ + col + 4);
            o[0] = (f16)v0.x; o[1] = (f16)v0.y; o[2] = (f16)v0.z; o[3] = (f16)v0.w;
            o[4] = (f16)v1.x; o[5] = (f16)v1.y; o[6] = (f16)v1.z; o[7] = (f16)v1.w;
        } else {
            for (int k = 0; k < 8; ++k) o[k] = (f16)0.f;
        }
        *reinterpret_cast<f16x8*>(w2p + i) = o;
    }
}

// ---------------- async global -> LDS, 16B per lane ----------------
__device__ __forceinline__ void gload_lds16(const f16* g, f16* l) {
    __builtin_amdgcn_global_load_lds(
        (const __attribute__((address_space(1))) void*)(g),
        (__attribute__((address_space(3))) void*)(l), 16, 0, 0);
}

// ---------------- m97-style 128x128 GEMM, C[M,N] = A[M,K] * B[N,K]^T ----------------
// EPI: 0 = plain store, 1 = relu store, 2 = qcos (N=16 valid; write qm_pad[M][32] with cos(q+theta))
template<typename CT, int EPI>
__global__ __launch_bounds__(256)
void gemm_bt(const f16* __restrict__ A, const f16* __restrict__ B, CT* __restrict__ C,
             int M, int N, int K, const float* __restrict__ theta)
{
    __shared__ __align__(16) f16 As[128 * 32];
    __shared__ __align__(16) f16 Bs[128 * 32];
    const int tid  = threadIdx.x;
    const int wave = tid >> 6;
    const int lane = tid & 63;
    const int m0 = blockIdx.y * 128;
    const int n0 = blockIdx.x * 128;
    const int wr = wave >> 1, wc = wave & 1;

    // staging: wave w owns tile rows [w*32, w*32+32), two 16-row instructions
    const int srow = wave * 32 + (lane >> 2);
    const f16* ag = A + (size_t)(m0 + srow) * K + (lane & 3) * 8;
    const f16* bg = B + (size_t)(n0 + srow) * K + (lane & 3) * 8;
    f16* al0 = As + wave * 1024;          // 32 elems/row * 16 rows = 512 per insn
    f16* al1 = As + wave * 1024 + 512;
    f16* bl0 = Bs + wave * 1024;
    f16* bl1 = Bs + wave * 1024 + 512;

    f32x4 acc[4][4] = {};
    const int fr = lane & 15, fq = lane >> 4;

    for (int kt = 0; kt < K; kt += 32) {
        gload_lds16(ag,                 al0);
        gload_lds16(ag + (size_t)16 * K, al1);
        gload_lds16(bg,                 bl0);
        gload_lds16(bg + (size_t)16 * K, bl1);
        ag += 32; bg += 32;
        __syncthreads();   // drains vmcnt before barrier -> tile visible

        f16x8 af[4], bf[4];
        #pragma unroll
        for (int mi = 0; mi < 4; ++mi)
            af[mi] = *reinterpret_cast<const f16x8*>(As + (wr * 64 + mi * 16 + fr) * 32 + fq * 8);
        #pragma unroll
        for (int ni = 0; ni < 4; ++ni)
            bf[ni] = *reinterpret_cast<const f16x8*>(Bs + (wc * 64 + ni * 16 + fr) * 32 + fq * 8);
        #pragma unroll
        for (int mi = 0; mi < 4; ++mi)
            #pragma unroll
            for (int ni = 0; ni < 4; ++ni)
                acc[mi][ni] = __builtin_amdgcn_mfma_f32_16x16x32_f16(af[mi], bf[ni], acc[mi][ni], 0, 0, 0);
        __syncthreads();   // all reads done before next stage overwrites
    }

    if constexpr (EPI == 2) {
        // only n-col 0..15 valid: wc==0, ni==0. C is qm_pad[M][32]; zero cols 16..31.
        if (wc == 0) {
            #pragma unroll
            for (int mi = 0; mi < 4; ++mi) {
                #pragma unroll
                for (int j = 0; j < 4; ++j) {
                    int row = m0 + wr * 64 + mi * 16 + fq * 4 + j;
                    float q = acc[mi][0][j] + theta[fr];
                    C[(size_t)row * 32 + fr]      = (CT)cosf(q);
                    C[(size_t)row * 32 + 16 + fr] = (CT)0.f;
                }
            }
        }
    } else {
        #pragma unroll
        for (int mi = 0; mi < 4; ++mi) {
            #pragma unroll
            for (int ni = 0; ni < 4; ++ni) {
                #pragma unroll
                for (int j = 0; j < 4; ++j) {
                    int row = m0 + wr * 64 + mi * 16 + fq * 4 + j;
                    int col = n0 + wc * 64 + ni * 16 + fr;
                    float v = acc[mi][ni][j];
                    if (EPI == 1) v = fmaxf(v, 0.f);
                    C[(size_t)row * N + col] = (CT)v;
                }
            }
        }
    }
}

extern "C" void kernel_launch(void* const* d_in, const int* in_sizes, int n_in,
                              void* d_out, int out_size, void* d_ws, size_t ws_size,
                              hipStream_t stream) {
    const float* x  = (const float*)d_in[0];
    const float* W1 = (const float*)d_in[1];
    const float* Wq = (const float*)d_in[2];
    const float* th = (const float*)d_in[3];
    const float* W2 = (const float*)d_in[4];
    const float* Wo = (const float*)d_in[5];
    float* out = (float*)d_out;

    f16* xh  = (f16*)d_ws;                         // 8192*1024
    f16* w1h = xh  + (size_t)M_TOT * E_DIM;        // 4096*1024
    f16* woh = w1h + (size_t)F_DIM * E_DIM;        // 1024*4096
    f16* wqp = woh + (size_t)E_DIM * F_DIM;        // 128*4096
    f16* w2p = wqp + (size_t)128 * F_DIM;          // 4096*32
    f16* qmp = w2p + (size_t)F_DIM * 32;           // 8192*32
    f16* h   = qmp + (size_t)M_TOT * 32;           // 8192*4096 (h, then h2 in-place)

    // 1) cast x, W1, Wo to f16   (16.8M elems / 8 per thread / 256 per block)
    cast_kernel<<<8192, 256, 0, stream>>>(x, W1, Wo, xh, w1h, woh);
    // 2) pad Wq -> [128][4096], W2 -> [4096][32]
    pad_kernel<<<320, 256, 0, stream>>>(Wq, W2, wqp, w2p);
    // 3) h = x @ W1^T           M=8192 N=4096 K=1024
    gemm_bt<f16, 0><<<dim3(32, 64), 256, 0, stream>>>(xh, w1h, h, M_TOT, F_DIM, E_DIM, nullptr);
    // 4) qm = cos(h @ Wq^T + theta)  (N=16 in padded 128; K=4096) -> qm_pad[8192][32]
    gemm_bt<f16, 2><<<dim3(1, 64), 256, 0, stream>>>(h, wqp, qmp, M_TOT, 128, F_DIM, th);
    // 5) h2 = relu(qm_pad @ W2p^T)   M=8192 N=4096 K=32 (in-place over h)
    gemm_bt<f16, 1><<<dim3(32, 64), 256, 0, stream>>>(qmp, w2p, h, M_TOT, F_DIM, 32, nullptr);
    // 6) out = h2 @ Wo^T        M=8192 N=1024 K=4096, f32 output
    gemm_bt<float, 0><<<dim3(8, 64), 256, 0, stream>>>(h, woh, out, M_TOT, E_DIM, F_DIM, nullptr);
}

// Round 2
// 273.920 us; speedup vs baseline: 1.1020x; 1.1020x over previous
//
#include <hip/hip_runtime.h>
#include <hip/hip_bf16.h>
#include <math.h>

typedef _Float16 f16;
typedef __attribute__((ext_vector_type(8))) _Float16 f16x8;
typedef __attribute__((ext_vector_type(4))) float f32x4;

#define M_TOT 8192      // BATCH*SEQ
#define E_DIM 1024
#define F_DIM 4096
#define NQ    16

// ---------------- cast f32 -> f16 for x, W1, Wo ----------------
__global__ __launch_bounds__(256) void cast_kernel(
    const float* __restrict__ x, const float* __restrict__ w1,
    const float* __restrict__ wo, f16* __restrict__ xh,
    f16* __restrict__ w1h, f16* __restrict__ woh)
{
    const size_t NX = (size_t)M_TOT * E_DIM;
    const size_t NW = (size_t)F_DIM * E_DIM;
    size_t i = ((size_t)blockIdx.x * 256 + threadIdx.x) * 8;
    const float* src; f16* dst; size_t off;
    if (i < NX)           { src = x;  dst = xh;  off = i; }
    else if (i < NX + NW) { src = w1; dst = w1h; off = i - NX; }
    else                  { src = wo; dst = woh; off = i - NX - NW; }
    float4 v0 = *reinterpret_cast<const float4*>(src + off);
    float4 v1 = *reinterpret_cast<const float4*>(src + off + 4);
    f16x8 o;
    o[0] = (f16)v0.x; o[1] = (f16)v0.y; o[2] = (f16)v0.z; o[3] = (f16)v0.w;
    o[4] = (f16)v1.x; o[5] = (f16)v1.y; o[6] = (f16)v1.z; o[7] = (f16)v1.w;
    *reinterpret_cast<f16x8*>(dst + off) = o;
}

// ------------- pad W2 -> [4096][32] f16 -------------
__global__ __launch_bounds__(256) void pad2_kernel(
    const float* __restrict__ W2, f16* __restrict__ w2p)
{
    int t = blockIdx.x * 256 + threadIdx.x;   // 16384 threads
    size_t i = (size_t)t * 8;                 // flat into [4096][32]
    int row = (int)(i >> 5);
    int col = (int)(i & 31);
    f16x8 o;
    if (col < NQ) {
        float4 v0 = *reinterpret_cast<const float4*>(W2 + (size_t)row * NQ + col);
        float4 v1 = *reinterpret_cast<const float4*>(W2 + (size_t)row * NQ + col + 4);
        o[0] = (f16)v0.x; o[1] = (f16)v0.y; o[2] = (f16)v0.z; o[3] = (f16)v0.w;
        o[4] = (f16)v1.x; o[5] = (f16)v1.y; o[6] = (f16)v1.z; o[7] = (f16)v1.w;
    } else {
        for (int k = 0; k < 8; ++k) o[k] = (f16)0.f;
    }
    *reinterpret_cast<f16x8*>(w2p + i) = o;
}

// ---------------- async global -> LDS, 16B per lane ----------------
__device__ __forceinline__ void gload_lds16(const f16* g, f16* l) {
    __builtin_amdgcn_global_load_lds(
        (const __attribute__((address_space(1))) void*)(g),
        (__attribute__((address_space(3))) void*)(l), 16, 0, 0);
}

// ---------------- 128x128 GEMM, C[M,N] = A[M,K_lda] * B[N,K_ldb]^T ----------------
// EPI: 0 = plain, 1 = relu. SPLIT: grid doubled; split0 -> C (CT), split1 -> Ch (f16 partial).
template<typename CT, int EPI, int SPLIT>
__global__ __launch_bounds__(256)
void gemm_bt(const f16* __restrict__ A, const f16* __restrict__ B,
             CT* __restrict__ C, f16* __restrict__ Ch,
             int gx, int K, int lda, int ldb, int ldc)
{
    __shared__ __align__(16) f16 As[128 * 32];
    __shared__ __align__(16) f16 Bs[128 * 32];
    const int tid  = threadIdx.x;
    const int wave = tid >> 6;
    const int lane = tid & 63;

    // XCD-aware bijective swizzle (grid % 8 == 0)
    const int nwg = gridDim.x;
    const int bid = blockIdx.x;
    const int cpx = nwg >> 3;
    int swz = (bid & 7) * cpx + (bid >> 3);
    const int per = SPLIT ? (nwg >> 1) : nwg;
    const int split = SPLIT ? (swz / per) : 0;
    const int r = SPLIT ? (swz % per) : swz;
    const int by = r / gx, bx = r % gx;

    const int m0 = by * 128;
    const int n0 = bx * 128;
    const int wr = wave >> 1, wc = wave & 1;

    const f16* Ab = A + (size_t)split * K;   // K is per-split length
    const f16* Bb = B + (size_t)split * K;

    const int srow = wave * 32 + (lane >> 2);
    const f16* ag = Ab + (size_t)(m0 + srow) * lda + (lane & 3) * 8;
    const f16* bg = Bb + (size_t)(n0 + srow) * ldb + (lane & 3) * 8;
    f16* al0 = As + wave * 1024;
    f16* al1 = As + wave * 1024 + 512;
    f16* bl0 = Bs + wave * 1024;
    f16* bl1 = Bs + wave * 1024 + 512;

    f32x4 acc[4][4] = {};
    const int fr = lane & 15, fq = lane >> 4;

    for (int kt = 0; kt < K; kt += 32) {
        gload_lds16(ag,                   al0);
        gload_lds16(ag + (size_t)16 * lda, al1);
        gload_lds16(bg,                   bl0);
        gload_lds16(bg + (size_t)16 * ldb, bl1);
        ag += 32; bg += 32;
        __syncthreads();

        f16x8 af[4], bf[4];
        #pragma unroll
        for (int mi = 0; mi < 4; ++mi)
            af[mi] = *reinterpret_cast<const f16x8*>(As + (wr * 64 + mi * 16 + fr) * 32 + fq * 8);
        #pragma unroll
        for (int ni = 0; ni < 4; ++ni)
            bf[ni] = *reinterpret_cast<const f16x8*>(Bs + (wc * 64 + ni * 16 + fr) * 32 + fq * 8);
        #pragma unroll
        for (int mi = 0; mi < 4; ++mi)
            #pragma unroll
            for (int ni = 0; ni < 4; ++ni)
                acc[mi][ni] = __builtin_amdgcn_mfma_f32_16x16x32_f16(af[mi], bf[ni], acc[mi][ni], 0, 0, 0);
        __syncthreads();
    }

    #pragma unroll
    for (int mi = 0; mi < 4; ++mi) {
        #pragma unroll
        for (int ni = 0; ni < 4; ++ni) {
            #pragma unroll
            for (int j = 0; j < 4; ++j) {
                int row = m0 + wr * 64 + mi * 16 + fq * 4 + j;
                int col = n0 + wc * 64 + ni * 16 + fr;
                float v = acc[mi][ni][j];
                if (EPI == 1) v = fmaxf(v, 0.f);
                if (SPLIT && split) Ch[(size_t)row * ldc + col] = (f16)v;
                else                C [(size_t)row * ldc + col] = (CT)v;
            }
        }
    }
}

// ---------------- skinny GEMM2: pq[kc][8192][16] f32 partials of h @ Wq^T ----------------
// grid: 512 blocks = (m-tile 64 rows x 128) * (kc x 4). Wq chunk [16][1024] f16 in LDS, swizzled.
__global__ __launch_bounds__(256) void qk_kernel(
    const f16* __restrict__ h, const float* __restrict__ Wq,
    float* __restrict__ pq)
{
    __shared__ __align__(16) f16 wqs[16 * 1024];
    const int tid  = threadIdx.x;
    const int wave = tid >> 6;
    const int lane = tid & 63;
    const int fr = lane & 15, fq = lane >> 4;

    const int bid = blockIdx.x;
    const int kc  = bid & 3;           // K chunk 0..3
    const int m0  = (bid >> 2) * 64;   // 64 rows per block

    // stage Wq[0..15][kc*1024 .. +1024) -> LDS f16, XOR-swizzled
    #pragma unroll
    for (int i = 0; i < 8; ++i) {
        int tau = i * 256 + tid;             // 0..2047
        int q   = tau >> 7;                  // 16 rows
        int kb  = tau & 127;                 // 128 chunks of 8
        const float* src = Wq + (size_t)q * F_DIM + kc * 1024 + kb * 8;
        float4 v0 = *reinterpret_cast<const float4*>(src);
        float4 v1 = *reinterpret_cast<const float4*>(src + 4);
        f16x8 o;
        o[0] = (f16)v0.x; o[1] = (f16)v0.y; o[2] = (f16)v0.z; o[3] = (f16)v0.w;
        o[4] = (f16)v1.x; o[5] = (f16)v1.y; o[6] = (f16)v1.z; o[7] = (f16)v1.w;
        int boff = (q * 2048 + kb * 16) ^ ((q & 7) << 4);
        *reinterpret_cast<f16x8*>((char*)wqs + boff) = o;
    }
    __syncthreads();

    const int arow = m0 + wave * 16 + fr;
    const f16* ha = h + (size_t)arow * F_DIM + kc * 1024 + fq * 8;

    f32x4 acc = {};
    #pragma unroll 8
    for (int kt = 0; kt < 1024; kt += 32) {
        f16x8 af = *reinterpret_cast<const f16x8*>(ha + kt);
        int boff = (fr * 2048 + (kt + fq * 8) * 2) ^ ((fr & 7) << 4);
        f16x8 bf = *reinterpret_cast<const f16x8*>((char*)wqs + boff);
        acc = __builtin_amdgcn_mfma_f32_16x16x32_f16(af, bf, acc, 0, 0, 0);
    }

    // C layout: col = lane&15 (=q), row = fq*4 + j
    #pragma unroll
    for (int j = 0; j < 4; ++j) {
        int row = m0 + wave * 16 + fq * 4 + j;
        pq[((size_t)kc * M_TOT + row) * NQ + fr] = acc[j];
    }
}

// ---------------- qreduce: qmp[8192][32] = cos(sum_kc pq + theta), zero-pad cols 16..31 ----------------
__global__ __launch_bounds__(256) void qreduce_kernel(
    const float* __restrict__ pq, const float* __restrict__ theta,
    f16* __restrict__ qmp)
{
    int t = blockIdx.x * 256 + threadIdx.x;    // 131072 threads
    int row = t >> 4, q = t & 15;
    size_t base = (size_t)row * NQ + q;
    float s = pq[base] + pq[(size_t)M_TOT * NQ + base]
            + pq[2 * (size_t)M_TOT * NQ + base] + pq[3 * (size_t)M_TOT * NQ + base];
    float v = cosf(s + theta[q]);
    qmp[(size_t)row * 32 + q]      = (f16)v;
    qmp[(size_t)row * 32 + 16 + q] = (f16)0.f;
}

// ---------------- out += (float)p1 ----------------
__global__ __launch_bounds__(256) void out_reduce_kernel(
    float* __restrict__ out, const f16* __restrict__ p1)
{
    size_t i = ((size_t)blockIdx.x * 256 + threadIdx.x) * 8;
    f16x8 p = *reinterpret_cast<const f16x8*>(p1 + i);
    float4 v0 = *reinterpret_cast<const float4*>(out + i);
    float4 v1 = *reinterpret_cast<const float4*>(out + i + 4);
    v0.x += (float)p[0]; v0.y += (float)p[1]; v0.z += (float)p[2]; v0.w += (float)p[3];
    v1.x += (float)p[4]; v1.y += (float)p[5]; v1.z += (float)p[6]; v1.w += (float)p[7];
    *reinterpret_cast<float4*>(out + i)     = v0;
    *reinterpret_cast<float4*>(out + i + 4) = v1;
}

extern "C" void kernel_launch(void* const* d_in, const int* in_sizes, int n_in,
                              void* d_out, int out_size, void* d_ws, size_t ws_size,
                              hipStream_t stream) {
    const float* x  = (const float*)d_in[0];
    const float* W1 = (const float*)d_in[1];
    const float* Wq = (const float*)d_in[2];
    const float* th = (const float*)d_in[3];
    const float* W2 = (const float*)d_in[4];
    const float* Wo = (const float*)d_in[5];
    float* out = (float*)d_out;

    f16* xh  = (f16*)d_ws;                         // 8,388,608 f16 (reused: pq then p1)
    f16* w1h = xh  + (size_t)M_TOT * E_DIM;        // 4,194,304
    f16* woh = w1h + (size_t)F_DIM * E_DIM;        // 4,194,304
    f16* w2p = woh + (size_t)E_DIM * F_DIM;        // 131,072
    f16* qmp = w2p + (size_t)F_DIM * 32;           // 262,144
    f16* h   = qmp + (size_t)M_TOT * 32;           // 33,554,432 (h, then h2 in-place)
    float* pq = (float*)xh;                        // 4*8192*16 f32 = 2 MB (dead after qreduce)
    f16*  p1  = xh;                                // 8192*1024 f16 = 16.8 MB (alive only in G4)

    // 1) casts
    cast_kernel<<<8192, 256, 0, stream>>>(x, W1, Wo, xh, w1h, woh);
    pad2_kernel<<<64, 256, 0, stream>>>(W2, w2p);
    // 2) h = x @ W1^T            M=8192 N=4096 K=1024
    gemm_bt<f16, 0, 0><<<2048, 256, 0, stream>>>(xh, w1h, h, nullptr, 32, E_DIM, E_DIM, E_DIM, F_DIM);
    // 3) q partials = h @ Wq^T   (split-K=4)
    qk_kernel<<<512, 256, 0, stream>>>(h, Wq, pq);
    // 4) qm = cos(sum + theta), padded to 32 cols
    qreduce_kernel<<<512, 256, 0, stream>>>(pq, th, qmp);
    // 5) h2 = relu(qmp @ w2p^T)  M=8192 N=4096 K=32 (in-place over h)
    gemm_bt<f16, 1, 0><<<2048, 256, 0, stream>>>(qmp, w2p, h, nullptr, 32, 32, 32, 32, F_DIM);
    // 6) out = h2 @ Wo^T         M=8192 N=1024 K=4096, split-K=2 in one launch
    gemm_bt<float, 0, 1><<<1024, 256, 0, stream>>>(h, woh, out, p1, 8, 2048, F_DIM, F_DIM, E_DIM);
    // 7) out += p1
    out_reduce_kernel<<<4096, 256, 0, stream>>>(out, p1);
}

// Round 3
// 201.791 us; speedup vs baseline: 1.4959x; 1.3574x over previous
//
#include <hip/hip_runtime.h>
#include <hip/hip_bf16.h>
#include <math.h>

typedef _Float16 f16;
typedef __attribute__((ext_vector_type(8))) _Float16 f16x8;
typedef __attribute__((ext_vector_type(4))) float f32x4;

#define M_TOT 8192      // BATCH*SEQ
#define E_DIM 1024
#define F_DIM 4096
#define NQ    16

#define BARRIER() asm volatile("s_barrier" ::: "memory")
#define WAITV(n)  asm volatile("s_waitcnt vmcnt(" #n ")" ::: "memory")

// ---------------- cast f32 -> f16 for x, W1, Wo ----------------
__global__ __launch_bounds__(256) void cast_kernel(
    const float* __restrict__ x, const float* __restrict__ w1,
    const float* __restrict__ wo, f16* __restrict__ xh,
    f16* __restrict__ w1h, f16* __restrict__ woh)
{
    const size_t NX = (size_t)M_TOT * E_DIM;
    const size_t NW = (size_t)F_DIM * E_DIM;
    size_t i = ((size_t)blockIdx.x * 256 + threadIdx.x) * 8;
    const float* src; f16* dst; size_t off;
    if (i < NX)           { src = x;  dst = xh;  off = i; }
    else if (i < NX + NW) { src = w1; dst = w1h; off = i - NX; }
    else                  { src = wo; dst = woh; off = i - NX - NW; }
    float4 v0 = *reinterpret_cast<const float4*>(src + off);
    float4 v1 = *reinterpret_cast<const float4*>(src + off + 4);
    f16x8 o;
    o[0] = (f16)v0.x; o[1] = (f16)v0.y; o[2] = (f16)v0.z; o[3] = (f16)v0.w;
    o[4] = (f16)v1.x; o[5] = (f16)v1.y; o[6] = (f16)v1.z; o[7] = (f16)v1.w;
    *reinterpret_cast<f16x8*>(dst + off) = o;
}

// ------------- pad W2 -> [4096][32] f16 -------------
__global__ __launch_bounds__(256) void pad2_kernel(
    const float* __restrict__ W2, f16* __restrict__ w2p)
{
    int t = blockIdx.x * 256 + threadIdx.x;
    size_t i = (size_t)t * 8;
    int row = (int)(i >> 5);
    int col = (int)(i & 31);
    f16x8 o;
    if (col < NQ) {
        float4 v0 = *reinterpret_cast<const float4*>(W2 + (size_t)row * NQ + col);
        float4 v1 = *reinterpret_cast<const float4*>(W2 + (size_t)row * NQ + col + 4);
        o[0] = (f16)v0.x; o[1] = (f16)v0.y; o[2] = (f16)v0.z; o[3] = (f16)v0.w;
        o[4] = (f16)v1.x; o[5] = (f16)v1.y; o[6] = (f16)v1.z; o[7] = (f16)v1.w;
    } else {
        for (int k = 0; k < 8; ++k) o[k] = (f16)0.f;
    }
    *reinterpret_cast<f16x8*>(w2p + i) = o;
}

__device__ __forceinline__ void gload_lds16(const f16* g, f16* l) {
    __builtin_amdgcn_global_load_lds(
        (const __attribute__((address_space(1))) void*)(g),
        (__attribute__((address_space(3))) void*)(l), 16, 0, 0);
}

// ================= 256x256 8-phase GEMM, C[M,N] = A[M,K]*B[N,K]^T (f16 in) =================
// 512 threads = 8 waves (2 wr x 4 wc); BK=64; LDS 128KB: [buf][A 16384 | B 16384] f16.
// LDS written linearly by global_load_lds; global SOURCE column pre-swizzled by
// slot^(row&7); ds_read applies the same XOR -> conflict-free-at-b128-floor reads.
// SPLIT: grid doubled; split0 -> C (CT), split1 -> Ch (f16 partial).
template<typename CT, int SPLIT>
__global__ __launch_bounds__(512, 2)
void gemm8p(const f16* __restrict__ A, const f16* __restrict__ B,
            CT* __restrict__ C, f16* __restrict__ Ch,
            int gx, int K, int lda, int ldb, int ldc)
{
    extern __shared__ __align__(16) f16 smem[];   // 65536 f16 = 128 KB
    const int tid  = threadIdx.x;
    const int w    = tid >> 6;
    const int lane = tid & 63;

    // XCD-aware swizzle (grid % 8 == 0), then split decode
    const int nwg = gridDim.x;
    const int bid = blockIdx.x;
    const int cpx = nwg >> 3;
    int swz = (bid & 7) * cpx + (bid >> 3);
    int split = 0, r = swz;
    if (SPLIT) { const int per = nwg >> 1; split = swz / per; r = swz % per; }
    const int by = r / gx, bx = r % gx;
    const int m0 = by * 256, n0 = bx * 256;

    const int wr = w >> 2, wc = w & 3;
    const int fr = lane & 15, fq = lane >> 4;

    const f16* Ab = A + (SPLIT ? (size_t)split * K : (size_t)0);
    const f16* Bb = B + (SPLIT ? (size_t)split * K : (size_t)0);

    // ---- staging addresses (per thread). Each gload: 512 thr x 16B = 64 rows x 128B.
    const int rl   = w * 8 + (lane >> 3);              // local row 0..63
    const int scol = (((lane & 7) ^ (rl & 7)) * 8);    // pre-swizzled source column (f16)
    const f16* gA = Ab + (size_t)(m0 + rl) * lda + scol;
    const f16* gB = Bb + (size_t)(n0 + rl) * ldb + scol;
    f16* lA = smem + w * 512;            // HW adds lane*16B
    f16* lB = smem + 16384 + w * 512;

#define SA(b,h,j,kt) gload_lds16(gA + (size_t)((h)*128 + (j)*64) * lda + (kt), lA + (b)*32768 + (h)*8192 + (j)*4096)
#define SB(b,h,j,kt) gload_lds16(gB + (size_t)((h)*128 + (j)*64) * ldb + (kt), lB + (b)*32768 + (h)*8192 + (j)*4096)
#define SAH(b,h,kt) do { SA(b,h,0,kt); SA(b,h,1,kt); } while(0)
#define SBH(b,h,kt) do { SB(b,h,0,kt); SB(b,h,1,kt); } while(0)

    // ---- fragment-read bases (f16 offsets); ds_read applies the same XOR
    const int xm  = fr & 7;
    const int so0 = ((0 + fq) ^ xm) * 8;               // ks=0 16B-slot
    const int so1 = ((4 + fq) ^ xm) * 8;               // ks=1
    const int aro = (wr * 128 + fr) * 64;
    const int bro = (wc * 64  + fr) * 64;

#define AF(b,m,ks) (*reinterpret_cast<const f16x8*>(smem + (b)*32768 + aro + (m)*1024 + so##ks))
#define BF(b,n,ks) (*reinterpret_cast<const f16x8*>(smem + (b)*32768 + 16384 + bro + (n)*1024 + so##ks))

    f32x4 acc[8][4] = {};
    f16x8 bf[4][2];

#define PHASE(b, p, STAGES, W4) do {                                              \
    f16x8 a00 = AF(b, 2*(p),   0), a01 = AF(b, 2*(p),   1);                       \
    f16x8 a10 = AF(b, 2*(p)+1, 0), a11 = AF(b, 2*(p)+1, 1);                       \
    if ((p) == 0) { _Pragma("unroll")                                             \
        for (int n = 0; n < 4; ++n) { bf[n][0] = BF(b,n,0); bf[n][1] = BF(b,n,1); } } \
    STAGES;                                                                       \
    BARRIER();                                                                    \
    __builtin_amdgcn_s_setprio(1);                                                \
    _Pragma("unroll") for (int n = 0; n < 4; ++n) {                               \
        acc[2*(p)  ][n] = __builtin_amdgcn_mfma_f32_16x16x32_f16(a00, bf[n][0], acc[2*(p)  ][n], 0,0,0); \
        acc[2*(p)+1][n] = __builtin_amdgcn_mfma_f32_16x16x32_f16(a10, bf[n][0], acc[2*(p)+1][n], 0,0,0); } \
    _Pragma("unroll") for (int n = 0; n < 4; ++n) {                               \
        acc[2*(p)  ][n] = __builtin_amdgcn_mfma_f32_16x16x32_f16(a01, bf[n][1], acc[2*(p)  ][n], 0,0,0); \
        acc[2*(p)+1][n] = __builtin_amdgcn_mfma_f32_16x16x32_f16(a11, bf[n][1], acc[2*(p)+1][n], 0,0,0); } \
    __builtin_amdgcn_s_setprio(0);                                                \
    if (W4) WAITV(4);                                                             \
    BARRIER(); } while(0)

    const int NT = K >> 6;      // K-tiles (even)
    const int NI = NT >> 1;

    // prologue: tile0 (A+B) -> buf0, tile1 B -> buf1
    SAH(0,0,0); SAH(0,1,0);
    SBH(0,0,0); SBH(0,1,0);
    SBH(1,0,64); SBH(1,1,64);
    WAITV(0);
    BARRIER();

    for (int i = 0; i < NI; ++i) {
        const int k1 = (2*i+1) << 6;
        int t2 = 2*i+2; if (t2 > NT-1) t2 = NT-1;
        int t3 = 2*i+3; if (t3 > NT-1) t3 = NT-1;
        const int k2 = t2 << 6, k3 = t3 << 6;
        // consumed-region schedule (proof in journal): staging only targets
        // half-tiles whose last reader finished before the previous barrier.
        PHASE(0, 0, SAH(1,0,k1),               0);   // P1
        PHASE(0, 1, SAH(1,1,k1); SBH(0,0,k2),  0);   // P2
        PHASE(0, 2, SBH(0,1,k2),               0);   // P3
        PHASE(0, 3, ,                          1);   // P4  vmcnt(4)
        PHASE(1, 0, SAH(0,0,k2),               0);   // P5
        PHASE(1, 1, SAH(0,1,k2); SBH(1,0,k3),  0);   // P6
        PHASE(1, 2, SBH(1,1,k3),               0);   // P7
        PHASE(1, 3, ,                          1);   // P8  vmcnt(4)
    }
    WAITV(0);

    #pragma unroll
    for (int m = 0; m < 8; ++m) {
        #pragma unroll
        for (int n = 0; n < 4; ++n) {
            #pragma unroll
            for (int j = 0; j < 4; ++j) {
                int row = m0 + wr * 128 + m * 16 + fq * 4 + j;
                int col = n0 + wc * 64  + n * 16 + fr;
                float v = acc[m][n][j];
                if (SPLIT && split) Ch[(size_t)row * ldc + col] = (f16)v;
                else                C [(size_t)row * ldc + col] = (CT)v;
            }
        }
    }
#undef SA
#undef SB
#undef SAH
#undef SBH
#undef AF
#undef BF
#undef PHASE
}

// ---------------- 128x128 GEMM (m97 structure) for the tiny-K GEMM5 ----------------
__global__ __launch_bounds__(256)
void gemm_bt_relu(const f16* __restrict__ A, const f16* __restrict__ B,
                  f16* __restrict__ C, int gx, int K, int lda, int ldb, int ldc)
{
    __shared__ __align__(16) f16 As[128 * 32];
    __shared__ __align__(16) f16 Bs[128 * 32];
    const int tid  = threadIdx.x;
    const int wave = tid >> 6;
    const int lane = tid & 63;
    const int nwg = gridDim.x;
    const int bid = blockIdx.x;
    const int cpx = nwg >> 3;
    int swz = (bid & 7) * cpx + (bid >> 3);
    const int by = swz / gx, bx = swz % gx;
    const int m0 = by * 128, n0 = bx * 128;
    const int wr = wave >> 1, wc = wave & 1;

    const int srow = wave * 32 + (lane >> 2);
    const f16* ag = A + (size_t)(m0 + srow) * lda + (lane & 3) * 8;
    const f16* bg = B + (size_t)(n0 + srow) * ldb + (lane & 3) * 8;
    f16* al0 = As + wave * 1024;
    f16* al1 = As + wave * 1024 + 512;
    f16* bl0 = Bs + wave * 1024;
    f16* bl1 = Bs + wave * 1024 + 512;

    f32x4 acc[4][4] = {};
    const int fr = lane & 15, fq = lane >> 4;

    for (int kt = 0; kt < K; kt += 32) {
        gload_lds16(ag,                    al0);
        gload_lds16(ag + (size_t)16 * lda, al1);
        gload_lds16(bg,                    bl0);
        gload_lds16(bg + (size_t)16 * ldb, bl1);
        ag += 32; bg += 32;
        __syncthreads();
        f16x8 af[4], bff[4];
        #pragma unroll
        for (int mi = 0; mi < 4; ++mi)
            af[mi] = *reinterpret_cast<const f16x8*>(As + (wr * 64 + mi * 16 + fr) * 32 + fq * 8);
        #pragma unroll
        for (int ni = 0; ni < 4; ++ni)
            bff[ni] = *reinterpret_cast<const f16x8*>(Bs + (wc * 64 + ni * 16 + fr) * 32 + fq * 8);
        #pragma unroll
        for (int mi = 0; mi < 4; ++mi)
            #pragma unroll
            for (int ni = 0; ni < 4; ++ni)
                acc[mi][ni] = __builtin_amdgcn_mfma_f32_16x16x32_f16(af[mi], bff[ni], acc[mi][ni], 0, 0, 0);
        __syncthreads();
    }

    #pragma unroll
    for (int mi = 0; mi < 4; ++mi)
        #pragma unroll
        for (int ni = 0; ni < 4; ++ni)
            #pragma unroll
            for (int j = 0; j < 4; ++j) {
                int row = m0 + wr * 64 + mi * 16 + fq * 4 + j;
                int col = n0 + wc * 64 + ni * 16 + fr;
                C[(size_t)row * ldc + col] = (f16)fmaxf(acc[mi][ni][j], 0.f);
            }
}

// ---------------- skinny GEMM2: pq[kc][8192][16] f32 partials of h @ Wq^T ----------------
__global__ __launch_bounds__(256) void qk_kernel(
    const f16* __restrict__ h, const float* __restrict__ Wq,
    float* __restrict__ pq)
{
    __shared__ __align__(16) f16 wqs[16 * 1024];
    const int tid  = threadIdx.x;
    const int wave = tid >> 6;
    const int lane = tid & 63;
    const int fr = lane & 15, fq = lane >> 4;

    const int bid = blockIdx.x;
    const int kc  = bid & 3;
    const int m0  = (bid >> 2) * 64;

    #pragma unroll
    for (int i = 0; i < 8; ++i) {
        int tau = i * 256 + tid;
        int q   = tau >> 7;
        int kb  = tau & 127;
        const float* src = Wq + (size_t)q * F_DIM + kc * 1024 + kb * 8;
        float4 v0 = *reinterpret_cast<const float4*>(src);
        float4 v1 = *reinterpret_cast<const float4*>(src + 4);
        f16x8 o;
        o[0] = (f16)v0.x; o[1] = (f16)v0.y; o[2] = (f16)v0.z; o[3] = (f16)v0.w;
        o[4] = (f16)v1.x; o[5] = (f16)v1.y; o[6] = (f16)v1.z; o[7] = (f16)v1.w;
        int boff = (q * 2048 + kb * 16) ^ ((q & 7) << 4);
        *reinterpret_cast<f16x8*>((char*)wqs + boff) = o;
    }
    __syncthreads();

    const int arow = m0 + wave * 16 + fr;
    const f16* ha = h + (size_t)arow * F_DIM + kc * 1024 + fq * 8;

    f32x4 acc = {};
    #pragma unroll 8
    for (int kt = 0; kt < 1024; kt += 32) {
        f16x8 af = *reinterpret_cast<const f16x8*>(ha + kt);
        int boff = (fr * 2048 + (kt + fq * 8) * 2) ^ ((fr & 7) << 4);
        f16x8 bf = *reinterpret_cast<const f16x8*>((char*)wqs + boff);
        acc = __builtin_amdgcn_mfma_f32_16x16x32_f16(af, bf, acc, 0, 0, 0);
    }
    #pragma unroll
    for (int j = 0; j < 4; ++j) {
        int row = m0 + wave * 16 + fq * 4 + j;
        pq[((size_t)kc * M_TOT + row) * NQ + fr] = acc[j];
    }
}

// ---------------- qreduce ----------------
__global__ __launch_bounds__(256) void qreduce_kernel(
    const float* __restrict__ pq, const float* __restrict__ theta,
    f16* __restrict__ qmp)
{
    int t = blockIdx.x * 256 + threadIdx.x;
    int row = t >> 4, q = t & 15;
    size_t base = (size_t)row * NQ + q;
    float s = pq[base] + pq[(size_t)M_TOT * NQ + base]
            + pq[2 * (size_t)M_TOT * NQ + base] + pq[3 * (size_t)M_TOT * NQ + base];
    float v = cosf(s + theta[q]);
    qmp[(size_t)row * 32 + q]      = (f16)v;
    qmp[(size_t)row * 32 + 16 + q] = (f16)0.f;
}

// ---------------- out += (float)p1 ----------------
__global__ __launch_bounds__(256) void out_reduce_kernel(
    float* __restrict__ out, const f16* __restrict__ p1)
{
    size_t i = ((size_t)blockIdx.x * 256 + threadIdx.x) * 8;
    f16x8 p = *reinterpret_cast<const f16x8*>(p1 + i);
    float4 v0 = *reinterpret_cast<const float4*>(out + i);
    float4 v1 = *reinterpret_cast<const float4*>(out + i + 4);
    v0.x += (float)p[0]; v0.y += (float)p[1]; v0.z += (float)p[2]; v0.w += (float)p[3];
    v1.x += (float)p[4]; v1.y += (float)p[5]; v1.z += (float)p[6]; v1.w += (float)p[7];
    *reinterpret_cast<float4*>(out + i)     = v0;
    *reinterpret_cast<float4*>(out + i + 4) = v1;
}

extern "C" void kernel_launch(void* const* d_in, const int* in_sizes, int n_in,
                              void* d_out, int out_size, void* d_ws, size_t ws_size,
                              hipStream_t stream) {
    const float* x  = (const float*)d_in[0];
    const float* W1 = (const float*)d_in[1];
    const float* Wq = (const float*)d_in[2];
    const float* th = (const float*)d_in[3];
    const float* W2 = (const float*)d_in[4];
    const float* Wo = (const float*)d_in[5];
    float* out = (float*)d_out;

    f16* xh  = (f16*)d_ws;                         // 8.39M f16 (reused: pq, then p1)
    f16* w1h = xh  + (size_t)M_TOT * E_DIM;
    f16* woh = w1h + (size_t)F_DIM * E_DIM;
    f16* w2p = woh + (size_t)E_DIM * F_DIM;
    f16* qmp = w2p + (size_t)F_DIM * 32;
    f16* h   = qmp + (size_t)M_TOT * 32;           // 33.5 MB (h, then h2 in-place)
    float* pq = (float*)xh;
    f16*  p1  = xh;

    // allow 128 KB dynamic LDS (ignore errors if default already sufficient)
    static bool attr_done = false;
    if (!attr_done) {
        hipFuncSetAttribute((const void*)&gemm8p<f16, 0>,
                            hipFuncAttributeMaxDynamicSharedMemorySize, 131072);
        hipFuncSetAttribute((const void*)&gemm8p<float, 1>,
                            hipFuncAttributeMaxDynamicSharedMemorySize, 131072);
        attr_done = true;
    }

    // 1) casts / pads
    cast_kernel<<<8192, 256, 0, stream>>>(x, W1, Wo, xh, w1h, woh);
    pad2_kernel<<<64, 256, 0, stream>>>(W2, w2p);
    // 2) h = x @ W1^T            M=8192 N=4096 K=1024  (256^2 8-phase)
    gemm8p<f16, 0><<<512, 512, 131072, stream>>>(xh, w1h, h, nullptr, 16, E_DIM, E_DIM, E_DIM, F_DIM);
    // 3) q partials = h @ Wq^T   (split-K=4)
    qk_kernel<<<512, 256, 0, stream>>>(h, Wq, pq);
    // 4) qm = cos(sum + theta)
    qreduce_kernel<<<512, 256, 0, stream>>>(pq, th, qmp);
    // 5) h2 = relu(qmp @ w2p^T)  M=8192 N=4096 K=32 (in-place over h)
    gemm_bt_relu<<<2048, 256, 0, stream>>>(qmp, w2p, h, 32, 32, 32, 32, F_DIM);
    // 6) out = h2 @ Wo^T         M=8192 N=1024 K=4096, split-K=2 (256 blocks = 1/CU)
    gemm8p<float, 1><<<256, 512, 131072, stream>>>(h, woh, out, p1, 4, 2048, F_DIM, F_DIM, E_DIM);
    // 7) out += p1
    out_reduce_kernel<<<4096, 256, 0, stream>>>(out, p1);
}

// Round 4
// 127.020 us; speedup vs baseline: 2.3764x; 1.5887x over previous
//
#include <hip/hip_runtime.h>
#include <hip/hip_bf16.h>
#include <math.h>

typedef _Float16 f16;
typedef __attribute__((ext_vector_type(8))) _Float16 f16x8;
typedef __attribute__((ext_vector_type(4))) float f32x4;

#define M_TOT 8192      // BATCH*SEQ
#define E_DIM 1024
#define F_DIM 4096
#define NQ    16

#define BARRIER() asm volatile("s_barrier" ::: "memory")
#define WAITV(n)  asm volatile("s_waitcnt vmcnt(" #n ")" ::: "memory")

__device__ __forceinline__ f16x8 cvt8(float4 a, float4 b) {
    f16x8 o;
    o[0] = (f16)a.x; o[1] = (f16)a.y; o[2] = (f16)a.z; o[3] = (f16)a.w;
    o[4] = (f16)b.x; o[5] = (f16)b.y; o[6] = (f16)b.z; o[7] = (f16)b.w;
    return o;
}

// ---------------- cast Wo f32 -> f16 ----------------
__global__ __launch_bounds__(256) void cast_wo_kernel(
    const float* __restrict__ wo, f16* __restrict__ woh)
{
    size_t i = ((size_t)blockIdx.x * 256 + threadIdx.x) * 8;
    float4 v0 = *reinterpret_cast<const float4*>(wo + i);
    float4 v1 = *reinterpret_cast<const float4*>(wo + i + 4);
    *reinterpret_cast<f16x8*>(woh + i) = cvt8(v0, v1);
}

// ---------------- W1 [4096][1024] f32 -> W1t [1024][4096] f16 (tiled transpose) ----------------
__global__ __launch_bounds__(256) void w1t_kernel(
    const float* __restrict__ W1, f16* __restrict__ W1t)
{
    __shared__ float ls[64][68];
    const int bf = blockIdx.x & 63;    // f-tile (4096/64)
    const int be = blockIdx.x >> 6;    // e-tile (1024/64)
    const int t  = threadIdx.x;
    const int r  = t >> 4;             // 0..15
    const int c4 = (t & 15) * 4;       // 0..60
    #pragma unroll
    for (int i = 0; i < 4; ++i) {
        int fr = r + i * 16;
        float4 v = *reinterpret_cast<const float4*>(W1 + (size_t)(bf * 64 + fr) * E_DIM + be * 64 + c4);
        ls[fr][c4] = v.x; ls[fr][c4 + 1] = v.y; ls[fr][c4 + 2] = v.z; ls[fr][c4 + 3] = v.w;
    }
    __syncthreads();
    const int er = t >> 2;             // 0..63
    const int fc = (t & 3) * 16;       // 0,16,32,48
    f16x8 o0, o1;
    #pragma unroll
    for (int j = 0; j < 8; ++j) { o0[j] = (f16)ls[fc + j][er]; o1[j] = (f16)ls[fc + 8 + j][er]; }
    f16* dst = W1t + (size_t)(be * 64 + er) * F_DIM + bf * 64 + fc;
    *reinterpret_cast<f16x8*>(dst)     = o0;
    *reinterpret_cast<f16x8*>(dst + 8) = o1;
}

// ------------- pad W2 -> [4096][32] f16 -------------
__global__ __launch_bounds__(256) void pad2_kernel(
    const float* __restrict__ W2, f16* __restrict__ w2p)
{
    int t = blockIdx.x * 256 + threadIdx.x;
    size_t i = (size_t)t * 8;
    int row = (int)(i >> 5);
    int col = (int)(i & 31);
    f16x8 o;
    if (col < NQ) {
        float4 v0 = *reinterpret_cast<const float4*>(W2 + (size_t)row * NQ + col);
        float4 v1 = *reinterpret_cast<const float4*>(W2 + (size_t)row * NQ + col + 4);
        o = cvt8(v0, v1);
    } else {
        for (int k = 0; k < 8; ++k) o[k] = (f16)0.f;
    }
    *reinterpret_cast<f16x8*>(w2p + i) = o;
}

// ---------------- tg: pT[kc][16][1024] f32 partials of T = Wq @ W1 ----------------
// grid 128 = 16 k-chunks(256) x 8 e-tiles(128). block 256 = 4 waves (32 e each).
__global__ __launch_bounds__(256) void tg_kernel(
    const float* __restrict__ Wq, const f16* __restrict__ W1t,
    float* __restrict__ pT)
{
    const int w = threadIdx.x >> 6, lane = threadIdx.x & 63;
    const int fr = lane & 15, fq = lane >> 4;
    const int kc = blockIdx.x & 15;
    const int et = blockIdx.x >> 4;
    const int e0 = et * 128 + w * 32;
    const int kbase = kc * 256;

    f32x4 acc[2] = {};
    #pragma unroll
    for (int s = 0; s < 8; ++s) {
        int k = kbase + s * 32 + fq * 8;
        float4 a0 = *reinterpret_cast<const float4*>(Wq + (size_t)fr * F_DIM + k);
        float4 a1 = *reinterpret_cast<const float4*>(Wq + (size_t)fr * F_DIM + k + 4);
        f16x8 af = cvt8(a0, a1);
        #pragma unroll
        for (int n = 0; n < 2; ++n) {
            f16x8 bf = *reinterpret_cast<const f16x8*>(W1t + (size_t)(e0 + n * 16 + fr) * F_DIM + k);
            acc[n] = __builtin_amdgcn_mfma_f32_16x16x32_f16(af, bf, acc[n], 0, 0, 0);
        }
    }
    #pragma unroll
    for (int n = 0; n < 2; ++n)
        #pragma unroll
        for (int j = 0; j < 4; ++j)
            pT[(size_t)kc * (16 * E_DIM) + (size_t)(fq * 4 + j) * E_DIM + e0 + n * 16 + fr] = acc[n][j];
}

// ---------------- treduce: Th[16][1024] f16 = sum_kc pT ----------------
__global__ __launch_bounds__(256) void treduce_kernel(
    const float* __restrict__ pT, f16* __restrict__ Th)
{
    int idx = blockIdx.x * 256 + threadIdx.x;   // 16384
    float s = 0.f;
    #pragma unroll
    for (int kc = 0; kc < 16; ++kc) s += pT[(size_t)kc * (16 * E_DIM) + idx];
    Th[idx] = (f16)s;
}

// ---------------- qx: pq2[kc][8192][16] f32 partials of q = x @ Th^T ----------------
// grid 256 = 2 k-halves(512) x 128 m-tiles(64 rows). block 256 = 4 waves.
__global__ __launch_bounds__(256) void qx_kernel(
    const float* __restrict__ x, const f16* __restrict__ Th,
    float* __restrict__ pq2)
{
    __shared__ __align__(16) f16 ths[16 * 512];
    const int tid = threadIdx.x, w = tid >> 6, lane = tid & 63;
    const int fr = lane & 15, fq = lane >> 4;
    const int kc = blockIdx.x & 1;
    const int m0 = (blockIdx.x >> 1) * 64;

    // stage Th[16][kc*512 .. +512) -> LDS, XOR-swizzled (16B slots, bits 4..6 ^ q&7)
    #pragma unroll
    for (int i = 0; i < 4; ++i) {
        int tau = i * 256 + tid;            // 0..1023
        int q   = tau >> 6;                 // 0..15
        int kb  = tau & 63;                 // chunks of 8 f16
        f16x8 v = *reinterpret_cast<const f16x8*>(Th + (size_t)q * E_DIM + kc * 512 + kb * 8);
        int boff = (q * 1024 + kb * 16) ^ ((q & 7) << 4);
        *reinterpret_cast<f16x8*>((char*)ths + boff) = v;
    }
    __syncthreads();

    const int row = m0 + w * 16 + fr;
    const float* xa = x + (size_t)row * E_DIM + kc * 512;
    f32x4 acc = {};
    #pragma unroll
    for (int s = 0; s < 16; ++s) {
        int ko = s * 32 + fq * 8;
        float4 a0 = *reinterpret_cast<const float4*>(xa + ko);
        float4 a1 = *reinterpret_cast<const float4*>(xa + ko + 4);
        f16x8 af = cvt8(a0, a1);
        int boff = (fr * 1024 + ko * 2) ^ ((fr & 7) << 4);
        f16x8 bf = *reinterpret_cast<const f16x8*>((char*)ths + boff);
        acc = __builtin_amdgcn_mfma_f32_16x16x32_f16(af, bf, acc, 0, 0, 0);
    }
    #pragma unroll
    for (int j = 0; j < 4; ++j)
        pq2[(size_t)kc * (M_TOT * NQ) + (size_t)(m0 + w * 16 + fq * 4 + j) * NQ + fr] = acc[j];
}

// ---------------- qfinal: qmp[8192][32] = cos(sum_kc pq2 + theta), zero-pad 16..31 ----------------
__global__ __launch_bounds__(256) void qfinal_kernel(
    const float* __restrict__ pq2, const float* __restrict__ theta,
    f16* __restrict__ qmp)
{
    int t = blockIdx.x * 256 + threadIdx.x;    // 131072
    int row = t >> 4, q = t & 15;
    float s = pq2[t] + pq2[(size_t)M_TOT * NQ + t];
    float v = cosf(s + theta[q]);
    qmp[(size_t)row * 32 + q]      = (f16)v;
    qmp[(size_t)row * 32 + 16 + q] = (f16)0.f;
}

__device__ __forceinline__ void gload_lds16(const f16* g, f16* l) {
    __builtin_amdgcn_global_load_lds(
        (const __attribute__((address_space(1))) void*)(g),
        (__attribute__((address_space(3))) void*)(l), 16, 0, 0);
}

// ================= 256x256 8-phase GEMM (proven round-3 structure) =================
template<typename CT, int SPLIT>
__global__ __launch_bounds__(512, 2)
void gemm8p(const f16* __restrict__ A, const f16* __restrict__ B,
            CT* __restrict__ C, f16* __restrict__ Ch,
            int gx, int K, int lda, int ldb, int ldc)
{
    extern __shared__ __align__(16) f16 smem[];   // 128 KB
    const int tid  = threadIdx.x;
    const int w    = tid >> 6;
    const int lane = tid & 63;

    const int nwg = gridDim.x;
    const int bid = blockIdx.x;
    const int cpx = nwg >> 3;
    int swz = (bid & 7) * cpx + (bid >> 3);
    int split = 0, r = swz;
    if (SPLIT) { const int per = nwg >> 1; split = swz / per; r = swz % per; }
    const int by = r / gx, bx = r % gx;
    const int m0 = by * 256, n0 = bx * 256;

    const int wr = w >> 2, wc = w & 3;
    const int fr = lane & 15, fq = lane >> 4;

    const f16* Ab = A + (SPLIT ? (size_t)split * K : (size_t)0);
    const f16* Bb = B + (SPLIT ? (size_t)split * K : (size_t)0);

    const int rl   = w * 8 + (lane >> 3);
    const int scol = (((lane & 7) ^ (rl & 7)) * 8);
    const f16* gA = Ab + (size_t)(m0 + rl) * lda + scol;
    const f16* gB = Bb + (size_t)(n0 + rl) * ldb + scol;
    f16* lA = smem + w * 512;
    f16* lB = smem + 16384 + w * 512;

#define SA(b,h,j,kt) gload_lds16(gA + (size_t)((h)*128 + (j)*64) * lda + (kt), lA + (b)*32768 + (h)*8192 + (j)*4096)
#define SB(b,h,j,kt) gload_lds16(gB + (size_t)((h)*128 + (j)*64) * ldb + (kt), lB + (b)*32768 + (h)*8192 + (j)*4096)
#define SAH(b,h,kt) do { SA(b,h,0,kt); SA(b,h,1,kt); } while(0)
#define SBH(b,h,kt) do { SB(b,h,0,kt); SB(b,h,1,kt); } while(0)

    const int xm  = fr & 7;
    const int so0 = ((0 + fq) ^ xm) * 8;
    const int so1 = ((4 + fq) ^ xm) * 8;
    const int aro = (wr * 128 + fr) * 64;
    const int bro = (wc * 64  + fr) * 64;

#define AF(b,m,ks) (*reinterpret_cast<const f16x8*>(smem + (b)*32768 + aro + (m)*1024 + so##ks))
#define BF(b,n,ks) (*reinterpret_cast<const f16x8*>(smem + (b)*32768 + 16384 + bro + (n)*1024 + so##ks))

    f32x4 acc[8][4] = {};
    f16x8 bf[4][2];

#define PHASE(b, p, STAGES, W4) do {                                              \
    f16x8 a00 = AF(b, 2*(p),   0), a01 = AF(b, 2*(p),   1);                       \
    f16x8 a10 = AF(b, 2*(p)+1, 0), a11 = AF(b, 2*(p)+1, 1);                       \
    if ((p) == 0) { _Pragma("unroll")                                             \
        for (int n = 0; n < 4; ++n) { bf[n][0] = BF(b,n,0); bf[n][1] = BF(b,n,1); } } \
    STAGES;                                                                       \
    BARRIER();                                                                    \
    __builtin_amdgcn_s_setprio(1);                                                \
    _Pragma("unroll") for (int n = 0; n < 4; ++n) {                               \
        acc[2*(p)  ][n] = __builtin_amdgcn_mfma_f32_16x16x32_f16(a00, bf[n][0], acc[2*(p)  ][n], 0,0,0); \
        acc[2*(p)+1][n] = __builtin_amdgcn_mfma_f32_16x16x32_f16(a10, bf[n][0], acc[2*(p)+1][n], 0,0,0); } \
    _Pragma("unroll") for (int n = 0; n < 4; ++n) {                               \
        acc[2*(p)  ][n] = __builtin_amdgcn_mfma_f32_16x16x32_f16(a01, bf[n][1], acc[2*(p)  ][n], 0,0,0); \
        acc[2*(p)+1][n] = __builtin_amdgcn_mfma_f32_16x16x32_f16(a11, bf[n][1], acc[2*(p)+1][n], 0,0,0); } \
    __builtin_amdgcn_s_setprio(0);                                                \
    if (W4) WAITV(4);                                                             \
    BARRIER(); } while(0)

    const int NT = K >> 6;
    const int NI = NT >> 1;

    SAH(0,0,0); SAH(0,1,0);
    SBH(0,0,0); SBH(0,1,0);
    SBH(1,0,64); SBH(1,1,64);
    WAITV(0);
    BARRIER();

    for (int i = 0; i < NI; ++i) {
        const int k1 = (2*i+1) << 6;
        int t2 = 2*i+2; if (t2 > NT-1) t2 = NT-1;
        int t3 = 2*i+3; if (t3 > NT-1) t3 = NT-1;
        const int k2 = t2 << 6, k3 = t3 << 6;
        PHASE(0, 0, SAH(1,0,k1),               0);
        PHASE(0, 1, SAH(1,1,k1); SBH(0,0,k2),  0);
        PHASE(0, 2, SBH(0,1,k2),               0);
        PHASE(0, 3, ,                          1);
        PHASE(1, 0, SAH(0,0,k2),               0);
        PHASE(1, 1, SAH(0,1,k2); SBH(1,0,k3),  0);
        PHASE(1, 2, SBH(1,1,k3),               0);
        PHASE(1, 3, ,                          1);
    }
    WAITV(0);

    #pragma unroll
    for (int m = 0; m < 8; ++m) {
        #pragma unroll
        for (int n = 0; n < 4; ++n) {
            #pragma unroll
            for (int j = 0; j < 4; ++j) {
                int row = m0 + wr * 128 + m * 16 + fq * 4 + j;
                int col = n0 + wc * 64  + n * 16 + fr;
                float v = acc[m][n][j];
                if (SPLIT && split) Ch[(size_t)row * ldc + col] = (f16)v;
                else                C [(size_t)row * ldc + col] = (CT)v;
            }
        }
    }
#undef SA
#undef SB
#undef SAH
#undef SBH
#undef AF
#undef BF
#undef PHASE
}

// ---------------- 128x128 GEMM (m97 structure) for tiny-K GEMM5 ----------------
__global__ __launch_bounds__(256)
void gemm_bt_relu(const f16* __restrict__ A, const f16* __restrict__ B,
                  f16* __restrict__ C, int gx, int K, int lda, int ldb, int ldc)
{
    __shared__ __align__(16) f16 As[128 * 32];
    __shared__ __align__(16) f16 Bs[128 * 32];
    const int tid  = threadIdx.x;
    const int wave = tid >> 6;
    const int lane = tid & 63;
    const int nwg = gridDim.x;
    const int bid = blockIdx.x;
    const int cpx = nwg >> 3;
    int swz = (bid & 7) * cpx + (bid >> 3);
    const int by = swz / gx, bx = swz % gx;
    const int m0 = by * 128, n0 = bx * 128;
    const int wr = wave >> 1, wc = wave & 1;

    const int srow = wave * 32 + (lane >> 2);
    const f16* ag = A + (size_t)(m0 + srow) * lda + (lane & 3) * 8;
    const f16* bg = B + (size_t)(n0 + srow) * ldb + (lane & 3) * 8;
    f16* al0 = As + wave * 1024;
    f16* al1 = As + wave * 1024 + 512;
    f16* bl0 = Bs + wave * 1024;
    f16* bl1 = Bs + wave * 1024 + 512;

    f32x4 acc[4][4] = {};
    const int fr = lane & 15, fq = lane >> 4;

    for (int kt = 0; kt < K; kt += 32) {
        gload_lds16(ag,                    al0);
        gload_lds16(ag + (size_t)16 * lda, al1);
        gload_lds16(bg,                    bl0);
        gload_lds16(bg + (size_t)16 * ldb, bl1);
        ag += 32; bg += 32;
        __syncthreads();
        f16x8 af[4], bff[4];
        #pragma unroll
        for (int mi = 0; mi < 4; ++mi)
            af[mi] = *reinterpret_cast<const f16x8*>(As + (wr * 64 + mi * 16 + fr) * 32 + fq * 8);
        #pragma unroll
        for (int ni = 0; ni < 4; ++ni)
            bff[ni] = *reinterpret_cast<const f16x8*>(Bs + (wc * 64 + ni * 16 + fr) * 32 + fq * 8);
        #pragma unroll
        for (int mi = 0; mi < 4; ++mi)
            #pragma unroll
            for (int ni = 0; ni < 4; ++ni)
                acc[mi][ni] = __builtin_amdgcn_mfma_f32_16x16x32_f16(af[mi], bff[ni], acc[mi][ni], 0, 0, 0);
        __syncthreads();
    }

    #pragma unroll
    for (int mi = 0; mi < 4; ++mi)
        #pragma unroll
        for (int ni = 0; ni < 4; ++ni)
            #pragma unroll
            for (int j = 0; j < 4; ++j) {
                int row = m0 + wr * 64 + mi * 16 + fq * 4 + j;
                int col = n0 + wc * 64 + ni * 16 + fr;
                C[(size_t)row * ldc + col] = (f16)fmaxf(acc[mi][ni][j], 0.f);
            }
}

// ---------------- out += (float)p1 ----------------
__global__ __launch_bounds__(256) void out_reduce_kernel(
    float* __restrict__ out, const f16* __restrict__ p1)
{
    size_t i = ((size_t)blockIdx.x * 256 + threadIdx.x) * 8;
    f16x8 p = *reinterpret_cast<const f16x8*>(p1 + i);
    float4 v0 = *reinterpret_cast<const float4*>(out + i);
    float4 v1 = *reinterpret_cast<const float4*>(out + i + 4);
    v0.x += (float)p[0]; v0.y += (float)p[1]; v0.z += (float)p[2]; v0.w += (float)p[3];
    v1.x += (float)p[4]; v1.y += (float)p[5]; v1.z += (float)p[6]; v1.w += (float)p[7];
    *reinterpret_cast<float4*>(out + i)     = v0;
    *reinterpret_cast<float4*>(out + i + 4) = v1;
}

extern "C" void kernel_launch(void* const* d_in, const int* in_sizes, int n_in,
                              void* d_out, int out_size, void* d_ws, size_t ws_size,
                              hipStream_t stream) {
    const float* x  = (const float*)d_in[0];
    const float* W1 = (const float*)d_in[1];
    const float* Wq = (const float*)d_in[2];
    const float* th = (const float*)d_in[3];
    const float* W2 = (const float*)d_in[4];
    const float* Wo = (const float*)d_in[5];
    float* out = (float*)d_out;

    // ws layout (101.45 MB total, identical footprint to round 3):
    char* base = (char*)d_ws;
    float* pT  = (float*)base;                          // 1 MB   (dead after treduce)
    f16*   Th  = (f16*)(base + (1 << 20));              // 32 KB  (dead after qx)
    float* pq2 = (float*)(base + (1 << 20) + (1 << 16));// 1 MB   (dead after qfinal)
    f16*   p1  = (f16*)base;                            // 16.8 MB (aliases above; live only G4->reduce)
    f16*   w1t = (f16*)(base + 16777216);               // 8.4 MB
    f16*   woh = w1t + (size_t)E_DIM * F_DIM;           // 8.4 MB
    f16*   w2p = woh + (size_t)E_DIM * F_DIM;           // 0.26 MB
    f16*   qmp = w2p + (size_t)F_DIM * 32;              // 0.52 MB
    f16*   h2  = qmp + (size_t)M_TOT * 32;              // 67.1 MB

    static bool attr_done = false;
    if (!attr_done) {
        hipFuncSetAttribute((const void*)&gemm8p<float, 1>,
                            hipFuncAttributeMaxDynamicSharedMemorySize, 131072);
        attr_done = true;
    }

    // 1) prep: W1 transpose-cast, Wo cast, W2 pad
    w1t_kernel<<<1024, 256, 0, stream>>>(W1, w1t);
    cast_wo_kernel<<<2048, 256, 0, stream>>>(Wo, woh);
    pad2_kernel<<<64, 256, 0, stream>>>(W2, w2p);
    // 2) T = Wq @ W1 (split-K=16 partials), reduce -> Th f16 [16][1024]
    tg_kernel<<<128, 256, 0, stream>>>(Wq, w1t, pT);
    treduce_kernel<<<64, 256, 0, stream>>>(pT, Th);
    // 3) q = x @ Th^T (split-K=2), finalize cos(q+theta) -> qmp [8192][32]
    qx_kernel<<<256, 256, 0, stream>>>(x, Th, pq2);
    qfinal_kernel<<<512, 256, 0, stream>>>(pq2, th, qmp);
    // 4) h2 = relu(qmp @ w2p^T)   M=8192 N=4096 K=32
    gemm_bt_relu<<<2048, 256, 0, stream>>>(qmp, w2p, h2, 32, 32, 32, 32, F_DIM);
    // 5) out = h2 @ Wo^T          M=8192 N=1024 K=4096, split-K=2
    gemm8p<float, 1><<<256, 512, 131072, stream>>>(h2, woh, out, p1, 4, 2048, F_DIM, F_DIM, E_DIM);
    // 6) out += p1
    out_reduce_kernel<<<4096, 256, 0, stream>>>(out, p1);
}

// Round 6
// 122.212 us; speedup vs baseline: 2.4699x; 1.0393x over previous
//
#include <hip/hip_runtime.h>
#include <hip/hip_bf16.h>
#include <math.h>

typedef _Float16 f16;
typedef __attribute__((ext_vector_type(8))) _Float16 f16x8;
typedef __attribute__((ext_vector_type(4))) _Float16 f16x4;
typedef __attribute__((ext_vector_type(4))) float f32x4;

#define M_TOT 8192      // BATCH*SEQ
#define E_DIM 1024
#define F_DIM 4096
#define NQ    16

#define BARRIER() asm volatile("s_barrier" ::: "memory")
#define WAITV(n)  asm volatile("s_waitcnt vmcnt(" #n ")" ::: "memory")
#define WAITLGKM() asm volatile("s_waitcnt lgkmcnt(0)" ::: "memory")

__device__ __forceinline__ f16x8 cvt8(float4 a, float4 b) {
    f16x8 o;
    o[0] = (f16)a.x; o[1] = (f16)a.y; o[2] = (f16)a.z; o[3] = (f16)a.w;
    o[4] = (f16)b.x; o[5] = (f16)b.y; o[6] = (f16)b.z; o[7] = (f16)b.w;
    return o;
}

// ---------------- cast Wo f32 -> f16 ----------------
__global__ __launch_bounds__(256) void cast_wo_kernel(
    const float* __restrict__ wo, f16* __restrict__ woh)
{
    size_t i = ((size_t)blockIdx.x * 256 + threadIdx.x) * 8;
    float4 v0 = *reinterpret_cast<const float4*>(wo + i);
    float4 v1 = *reinterpret_cast<const float4*>(wo + i + 4);
    *reinterpret_cast<f16x8*>(woh + i) = cvt8(v0, v1);
}

// ---------------- W1 [4096][1024] f32 -> W1t [1024][4096] f16 ----------------
__global__ __launch_bounds__(256) void w1t_kernel(
    const float* __restrict__ W1, f16* __restrict__ W1t)
{
    __shared__ float ls[64][68];
    const int bf = blockIdx.x & 63;
    const int be = blockIdx.x >> 6;
    const int t  = threadIdx.x;
    const int r  = t >> 4;
    const int c4 = (t & 15) * 4;
    #pragma unroll
    for (int i = 0; i < 4; ++i) {
        int fr = r + i * 16;
        float4 v = *reinterpret_cast<const float4*>(W1 + (size_t)(bf * 64 + fr) * E_DIM + be * 64 + c4);
        ls[fr][c4] = v.x; ls[fr][c4 + 1] = v.y; ls[fr][c4 + 2] = v.z; ls[fr][c4 + 3] = v.w;
    }
    __syncthreads();
    const int er = t >> 2;
    const int fc = (t & 3) * 16;
    f16x8 o0, o1;
    #pragma unroll
    for (int j = 0; j < 8; ++j) { o0[j] = (f16)ls[fc + j][er]; o1[j] = (f16)ls[fc + 8 + j][er]; }
    f16* dst = W1t + (size_t)(be * 64 + er) * F_DIM + bf * 64 + fc;
    *reinterpret_cast<f16x8*>(dst)     = o0;
    *reinterpret_cast<f16x8*>(dst + 8) = o1;
}

// ------------- pad W2 -> [4096][32] f16 -------------
__global__ __launch_bounds__(256) void pad2_kernel(
    const float* __restrict__ W2, f16* __restrict__ w2p)
{
    int t = blockIdx.x * 256 + threadIdx.x;
    size_t i = (size_t)t * 8;
    int row = (int)(i >> 5);
    int col = (int)(i & 31);
    f16x8 o;
    if (col < NQ) {
        float4 v0 = *reinterpret_cast<const float4*>(W2 + (size_t)row * NQ + col);
        float4 v1 = *reinterpret_cast<const float4*>(W2 + (size_t)row * NQ + col + 4);
        o = cvt8(v0, v1);
    } else {
        for (int k = 0; k < 8; ++k) o[k] = (f16)0.f;
    }
    *reinterpret_cast<f16x8*>(w2p + i) = o;
}

// ---------------- tg: pT[kc][16][1024] f32 partials of T = Wq @ W1 ----------------
__global__ __launch_bounds__(256) void tg_kernel(
    const float* __restrict__ Wq, const f16* __restrict__ W1t,
    float* __restrict__ pT)
{
    const int w = threadIdx.x >> 6, lane = threadIdx.x & 63;
    const int fr = lane & 15, fq = lane >> 4;
    const int kc = blockIdx.x & 15;
    const int et = blockIdx.x >> 4;
    const int e0 = et * 128 + w * 32;
    const int kbase = kc * 256;

    f32x4 acc[2] = {};
    #pragma unroll
    for (int s = 0; s < 8; ++s) {
        int k = kbase + s * 32 + fq * 8;
        float4 a0 = *reinterpret_cast<const float4*>(Wq + (size_t)fr * F_DIM + k);
        float4 a1 = *reinterpret_cast<const float4*>(Wq + (size_t)fr * F_DIM + k + 4);
        f16x8 af = cvt8(a0, a1);
        #pragma unroll
        for (int n = 0; n < 2; ++n) {
            f16x8 bf = *reinterpret_cast<const f16x8*>(W1t + (size_t)(e0 + n * 16 + fr) * F_DIM + k);
            acc[n] = __builtin_amdgcn_mfma_f32_16x16x32_f16(af, bf, acc[n], 0, 0, 0);
        }
    }
    #pragma unroll
    for (int n = 0; n < 2; ++n)
        #pragma unroll
        for (int j = 0; j < 4; ++j)
            pT[(size_t)kc * (16 * E_DIM) + (size_t)(fq * 4 + j) * E_DIM + e0 + n * 16 + fr] = acc[n][j];
}

// ---------------- treduce: Th[16][1024] f16 = sum_kc pT ----------------
__global__ __launch_bounds__(256) void treduce_kernel(
    const float* __restrict__ pT, f16* __restrict__ Th)
{
    int idx = blockIdx.x * 256 + threadIdx.x;
    float s = 0.f;
    #pragma unroll
    for (int kc = 0; kc < 16; ++kc) s += pT[(size_t)kc * (16 * E_DIM) + idx];
    Th[idx] = (f16)s;
}

// ---------------- qx: pq2[kc][8192][16] f32 partials of q = x @ Th^T ----------------
__global__ __launch_bounds__(256) void qx_kernel(
    const float* __restrict__ x, const f16* __restrict__ Th,
    float* __restrict__ pq2)
{
    __shared__ __align__(16) f16 ths[16 * 512];
    const int tid = threadIdx.x, w = tid >> 6, lane = tid & 63;
    const int fr = lane & 15, fq = lane >> 4;
    const int kc = blockIdx.x & 1;
    const int m0 = (blockIdx.x >> 1) * 64;

    #pragma unroll
    for (int i = 0; i < 4; ++i) {
        int tau = i * 256 + tid;
        int q   = tau >> 6;
        int kb  = tau & 63;
        f16x8 v = *reinterpret_cast<const f16x8*>(Th + (size_t)q * E_DIM + kc * 512 + kb * 8);
        int boff = (q * 1024 + kb * 16) ^ ((q & 7) << 4);
        *reinterpret_cast<f16x8*>((char*)ths + boff) = v;
    }
    __syncthreads();

    const int row = m0 + w * 16 + fr;
    const float* xa = x + (size_t)row * E_DIM + kc * 512;
    f32x4 acc = {};
    #pragma unroll
    for (int s = 0; s < 16; ++s) {
        int ko = s * 32 + fq * 8;
        float4 a0 = *reinterpret_cast<const float4*>(xa + ko);
        float4 a1 = *reinterpret_cast<const float4*>(xa + ko + 4);
        f16x8 af = cvt8(a0, a1);
        int boff = (fr * 1024 + ko * 2) ^ ((fr & 7) << 4);
        f16x8 bf = *reinterpret_cast<const f16x8*>((char*)ths + boff);
        acc = __builtin_amdgcn_mfma_f32_16x16x32_f16(af, bf, acc, 0, 0, 0);
    }
    #pragma unroll
    for (int j = 0; j < 4; ++j)
        pq2[(size_t)kc * (M_TOT * NQ) + (size_t)(m0 + w * 16 + fq * 4 + j) * NQ + fr] = acc[j];
}

// ---------------- qfinal: qmp[8192][32] = cos(sum + theta), zero-pad 16..31 ----------------
__global__ __launch_bounds__(256) void qfinal_kernel(
    const float* __restrict__ pq2, const float* __restrict__ theta,
    f16* __restrict__ qmp)
{
    int t = blockIdx.x * 256 + threadIdx.x;
    int row = t >> 4, q = t & 15;
    float s = pq2[t] + pq2[(size_t)M_TOT * NQ + t];
    float v = cosf(s + theta[q]);
    qmp[(size_t)row * 32 + q]      = (f16)v;
    qmp[(size_t)row * 32 + 16 + q] = (f16)0.f;
}

__device__ __forceinline__ void gload_lds16(const f16* g, f16* l) {
    __builtin_amdgcn_global_load_lds(
        (const __attribute__((address_space(1))) void*)(g),
        (__attribute__((address_space(3))) void*)(l), 16, 0, 0);
}

// ================= fused GEMM: out = relu(qm @ W2^T) @ Wo^T, 256x256 8-phase =================
// A-tiles (h2) PRODUCED in-kernel: mini-MFMA of w2 K-slice (global->reg, L2-resident)
// x qm (LDS-resident, swizzled), relu+cvt, ds_write into the swizzled A-layout.
// LDS layout (f16 units): buf b in [b*32768, b*32768+32768) = { A[b] @ +0 (16384),
// B[b] @ +16384 (16384) }; qmS @ 65536 (8192). Total 73728 f16 = 147456 B.
__global__ __launch_bounds__(512, 2)
void gemm4f(const f16* __restrict__ qmp, const f16* __restrict__ w2p,
            const f16* __restrict__ Wo, f16* __restrict__ P0, f16* __restrict__ P1)
{
    extern __shared__ __align__(16) f16 smem[];
    const int tid  = threadIdx.x;
    const int w    = tid >> 6;
    const int lane = tid & 63;

    const int nwg = gridDim.x;              // 256
    const int bid = blockIdx.x;
    const int cpx = nwg >> 3;
    int swz = (bid & 7) * cpx + (bid >> 3);
    const int per = nwg >> 1;               // 128
    const int split = swz / per;
    const int r = swz % per;
    const int by = r >> 2, bx = r & 3;      // gx = 4
    const int m0 = by * 256, n0 = bx * 256;

    const int wr = w >> 2, wc = w & 3;
    const int fr = lane & 15, fq = lane >> 4;
    const int K = 2048;                     // per split

    const f16* Bb  = Wo + (size_t)split * K;
    const f16* w2g = w2p + (size_t)split * K * 32;
    f16* Pout = split ? P1 : P0;

    // ---- B staging ----
    const int rl   = w * 8 + (lane >> 3);
    const int scol = (((lane & 7) ^ (rl & 7)) * 8);
    const f16* gB = Bb + (size_t)(n0 + rl) * F_DIM + scol;
    f16* lB = smem + 16384 + w * 512;       // B[b] @ b*32768 + 16384 (f16 units)

#define SB(b,h,j,kt) gload_lds16(gB + (size_t)((h)*128 + (j)*64) * F_DIM + (kt), lB + (b)*32768 + (h)*8192 + (j)*4096)
#define SBH(b,h,kt) do { SB(b,h,0,kt); SB(b,h,1,kt); } while(0)

    // ---- qm staging: rows m0..m0+255 -> qmS [256][32] f16, slot ^= row&3 ----
    f16* qmS = smem + 65536;
    {
        const int qrow = w * 16 + (lane >> 2);
        const f16* qsrc = qmp + (size_t)(m0 + qrow) * 32 + (((lane & 3) ^ (qrow & 3)) << 3);
        f16* qdst = qmS + w * 512;
        gload_lds16(qsrc, qdst);
        gload_lds16(qsrc + 128 * 32, qdst + 4096);
    }

    // ---- w2 fragment register loads (A-operand of mini-GEMM) ----
    f16x8 w2a[4], w2b[4];
#define LOADW2(R, kt) do { _Pragma("unroll") \
    for (int ft = 0; ft < 4; ++ft) \
        R[ft] = *reinterpret_cast<const f16x8*>(w2g + (size_t)((kt) + ft*16 + fr) * 32 + fq * 8); } while(0)

    // ---- produce A[bdst] = relu(qm @ w2[kt]^T) in swizzled layout ----
    const int mt0 = 2 * w;
#define PRODUCE(bdst, W2R) do {                                                   \
    const int r0_ = mt0 * 16 + fr, r1_ = r0_ + 16;                                \
    f16x8 q0_ = *reinterpret_cast<const f16x8*>(qmS + r0_ * 32 + ((fq ^ (fr & 3)) << 3)); \
    f16x8 q1_ = *reinterpret_cast<const f16x8*>(qmS + r1_ * 32 + ((fq ^ (fr & 3)) << 3)); \
    f32x4 z_ = {0.f, 0.f, 0.f, 0.f};                                              \
    _Pragma("unroll") for (int ft = 0; ft < 4; ++ft) {                            \
        f32x4 c0_ = __builtin_amdgcn_mfma_f32_16x16x32_f16(W2R[ft], q0_, z_, 0, 0, 0); \
        f32x4 c1_ = __builtin_amdgcn_mfma_f32_16x16x32_f16(W2R[ft], q1_, z_, 0, 0, 0); \
        f16x4 h0_, h1_;                                                           \
        _Pragma("unroll") for (int jj = 0; jj < 4; ++jj) {                        \
            h0_[jj] = (f16)fmaxf(c0_[jj], 0.f); h1_[jj] = (f16)fmaxf(c1_[jj], 0.f); } \
        const int sl_ = (2 * ft + (fq >> 1)) ^ (fr & 7);                          \
        *reinterpret_cast<f16x4*>(smem + (bdst)*32768 + r0_*64 + sl_*8 + ((fq & 1) << 2)) = h0_; \
        *reinterpret_cast<f16x4*>(smem + (bdst)*32768 + r1_*64 + sl_*8 + ((fq & 1) << 2)) = h1_; \
    } } while(0)

    // ---- main fragment-read bases ----
    const int xm  = fr & 7;
    const int so0 = ((0 + fq) ^ xm) * 8;
    const int so1 = ((4 + fq) ^ xm) * 8;
    const int aro = (wr * 128 + fr) * 64;
    const int bro = (wc * 64  + fr) * 64;

#define AF(b,m,ks) (*reinterpret_cast<const f16x8*>(smem + (b)*32768 + aro + (m)*1024 + so##ks))
#define BF(b,n,ks) (*reinterpret_cast<const f16x8*>(smem + (b)*32768 + 16384 + bro + (n)*1024 + so##ks))

    f32x4 acc[8][4] = {};
    f16x8 bf[4][2];

#define PHASE(b, p, STAGES, W4) do {                                              \
    f16x8 a00 = AF(b, 2*(p),   0), a01 = AF(b, 2*(p),   1);                       \
    f16x8 a10 = AF(b, 2*(p)+1, 0), a11 = AF(b, 2*(p)+1, 1);                       \
    if ((p) == 0) { _Pragma("unroll")                                             \
        for (int n = 0; n < 4; ++n) { bf[n][0] = BF(b,n,0); bf[n][1] = BF(b,n,1); } } \
    STAGES;                                                                       \
    BARRIER();                                                                    \
    __builtin_amdgcn_s_setprio(1);                                                \
    _Pragma("unroll") for (int n = 0; n < 4; ++n) {                               \
        acc[2*(p)  ][n] = __builtin_amdgcn_mfma_f32_16x16x32_f16(a00, bf[n][0], acc[2*(p)  ][n], 0,0,0); \
        acc[2*(p)+1][n] = __builtin_amdgcn_mfma_f32_16x16x32_f16(a10, bf[n][0], acc[2*(p)+1][n], 0,0,0); } \
    _Pragma("unroll") for (int n = 0; n < 4; ++n) {                               \
        acc[2*(p)  ][n] = __builtin_amdgcn_mfma_f32_16x16x32_f16(a01, bf[n][1], acc[2*(p)  ][n], 0,0,0); \
        acc[2*(p)+1][n] = __builtin_amdgcn_mfma_f32_16x16x32_f16(a11, bf[n][1], acc[2*(p)+1][n], 0,0,0); } \
    __builtin_amdgcn_s_setprio(0);                                                \
    if (W4) { WAITV(8); WAITLGKM(); }                                             \
    BARRIER(); } while(0)

    const int NT = K >> 6;      // 32
    const int NI = NT >> 1;     // 16

    // prologue: w2[k0],w2[k1] -> regs; B0<-k0, B1<-k1; qm -> LDS; produce A[0]
    LOADW2(w2b, 0);
    LOADW2(w2a, 64);
    SBH(0,0,0);  SBH(0,1,0);
    SBH(1,0,64); SBH(1,1,64);
    WAITV(0);
    BARRIER();
    PRODUCE(0, w2b);
    WAITLGKM();
    BARRIER();

    for (int i = 0; i < NI; ++i) {
        const int k1 = (2*i+1) << 6;
        int t2 = 2*i+2; if (t2 > NT-1) t2 = NT-1;
        int t3 = 2*i+3; if (t3 > NT-1) t3 = NT-1;
        const int k2 = t2 << 6, k3 = t3 << 6;
        PHASE(0, 0, PRODUCE(1, w2a),            0);   // P1: produce A[1]<-k1
        PHASE(0, 1, LOADW2(w2b, k2); SBH(0,0,k2), 0); // P2
        PHASE(0, 2, SBH(0,1,k2),                0);   // P3
        PHASE(0, 3, ,                           1);   // P4: vmcnt(8)+lgkm(0)
        PHASE(1, 0, PRODUCE(0, w2b),            0);   // P5: produce A[0]<-k2
        PHASE(1, 1, LOADW2(w2a, k3); SBH(1,0,k3), 0); // P6
        PHASE(1, 2, SBH(1,1,k3),                0);   // P7
        PHASE(1, 3, ,                           1);   // P8: vmcnt(8)+lgkm(0)
    }
    WAITV(0);

    #pragma unroll
    for (int m = 0; m < 8; ++m) {
        #pragma unroll
        for (int n = 0; n < 4; ++n) {
            #pragma unroll
            for (int j = 0; j < 4; ++j) {
                int row = m0 + wr * 128 + m * 16 + fq * 4 + j;
                int col = n0 + wc * 64  + n * 16 + fr;
                Pout[(size_t)row * E_DIM + col] = (f16)acc[m][n][j];
            }
        }
    }
#undef SB
#undef SBH
#undef LOADW2
#undef PRODUCE
#undef AF
#undef BF
#undef PHASE
}

// ---------------- out = (float)p0 + (float)p1 ----------------
__global__ __launch_bounds__(256) void out_reduce2_kernel(
    float* __restrict__ out, const f16* __restrict__ p0, const f16* __restrict__ p1)
{
    size_t i = ((size_t)blockIdx.x * 256 + threadIdx.x) * 8;
    f16x8 a = *reinterpret_cast<const f16x8*>(p0 + i);
    f16x8 b = *reinterpret_cast<const f16x8*>(p1 + i);
    float4 v0, v1;
    v0.x = (float)a[0] + (float)b[0]; v0.y = (float)a[1] + (float)b[1];
    v0.z = (float)a[2] + (float)b[2]; v0.w = (float)a[3] + (float)b[3];
    v1.x = (float)a[4] + (float)b[4]; v1.y = (float)a[5] + (float)b[5];
    v1.z = (float)a[6] + (float)b[6]; v1.w = (float)a[7] + (float)b[7];
    *reinterpret_cast<float4*>(out + i)     = v0;
    *reinterpret_cast<float4*>(out + i + 4) = v1;
}

extern "C" void kernel_launch(void* const* d_in, const int* in_sizes, int n_in,
                              void* d_out, int out_size, void* d_ws, size_t ws_size,
                              hipStream_t stream) {
    const float* x  = (const float*)d_in[0];
    const float* W1 = (const float*)d_in[1];
    const float* Wq = (const float*)d_in[2];
    const float* th = (const float*)d_in[3];
    const float* W2 = (const float*)d_in[4];
    const float* Wo = (const float*)d_in[5];
    float* out = (float*)d_out;

    char* base = (char*)d_ws;
    float* pT  = (float*)base;                            // 1 MB   (dead after treduce)
    f16*   Th  = (f16*)(base + (1 << 20));                // 32 KB  (dead after qx)
    float* pq2 = (float*)(base + (1 << 20) + (1 << 16));  // 1 MB   (dead after qfinal)
    f16*   w1t = (f16*)(base + 16777216);                 // 8.4 MB
    f16*   woh = w1t + (size_t)E_DIM * F_DIM;             // 8.4 MB
    f16*   w2p = woh + (size_t)E_DIM * F_DIM;             // 0.26 MB
    f16*   qmp = w2p + (size_t)F_DIM * 32;                // 0.52 MB
    f16*   p0  = qmp + (size_t)M_TOT * 32;                // 16.8 MB
    f16*   p1  = p0  + (size_t)M_TOT * E_DIM;             // 16.8 MB

    static bool attr_done = false;
    if (!attr_done) {
        hipFuncSetAttribute((const void*)&gemm4f,
                            hipFuncAttributeMaxDynamicSharedMemorySize, 147456);
        attr_done = true;
    }

    // 1) prep
    w1t_kernel<<<1024, 256, 0, stream>>>(W1, w1t);
    cast_wo_kernel<<<2048, 256, 0, stream>>>(Wo, woh);
    pad2_kernel<<<64, 256, 0, stream>>>(W2, w2p);
    // 2) T = Wq @ W1 -> Th f16 [16][1024]
    tg_kernel<<<128, 256, 0, stream>>>(Wq, w1t, pT);
    treduce_kernel<<<64, 256, 0, stream>>>(pT, Th);
    // 3) q = x @ Th^T, cos(q+theta) -> qmp [8192][32]
    qx_kernel<<<256, 256, 0, stream>>>(x, Th, pq2);
    qfinal_kernel<<<512, 256, 0, stream>>>(pq2, th, qmp);
    // 4) fused: out-partials = relu(qmp @ w2p^T) @ Wo^T, split-K=2, f16 partials
    gemm4f<<<256, 512, 147456, stream>>>(qmp, w2p, woh, p0, p1);
    // 5) out = p0 + p1
    out_reduce2_kernel<<<4096, 256, 0, stream>>>(out, p0, p1);
}

// Round 7
// 115.070 us; speedup vs baseline: 2.6232x; 1.0621x over previous
//
#include <hip/hip_runtime.h>
#include <hip/hip_bf16.h>
#include <math.h>

typedef _Float16 f16;
typedef __attribute__((ext_vector_type(8))) _Float16 f16x8;
typedef __attribute__((ext_vector_type(4))) _Float16 f16x4;
typedef __attribute__((ext_vector_type(4))) float f32x4;

#define M_TOT 8192      // BATCH*SEQ
#define E_DIM 1024
#define F_DIM 4096
#define NQ    16

#define BARRIER() asm volatile("s_barrier" ::: "memory")
#define WAITV(n)  asm volatile("s_waitcnt vmcnt(" #n ")" ::: "memory")
#define WAITLGKM() asm volatile("s_waitcnt lgkmcnt(0)" ::: "memory")

__device__ __forceinline__ f16x8 cvt8(float4 a, float4 b) {
    f16x8 o;
    o[0] = (f16)a.x; o[1] = (f16)a.y; o[2] = (f16)a.z; o[3] = (f16)a.w;
    o[4] = (f16)b.x; o[5] = (f16)b.y; o[6] = (f16)b.z; o[7] = (f16)b.w;
    return o;
}

// ---------------- merged prep: W1 transpose-cast | Wo cast | W2 pad ----------------
__global__ __launch_bounds__(256) void prep_kernel(
    const float* __restrict__ W1, f16* __restrict__ W1t,
    const float* __restrict__ wo, f16* __restrict__ woh,
    const float* __restrict__ W2, f16* __restrict__ w2p)
{
    __shared__ float ls[64][68];
    const int b = blockIdx.x;
    if (b < 1024) {
        // W1 [4096][1024] f32 -> W1t [1024][4096] f16
        const int bf = b & 63;
        const int be = b >> 6;
        const int t  = threadIdx.x;
        const int r  = t >> 4;
        const int c4 = (t & 15) * 4;
        #pragma unroll
        for (int i = 0; i < 4; ++i) {
            int fr = r + i * 16;
            float4 v = *reinterpret_cast<const float4*>(W1 + (size_t)(bf * 64 + fr) * E_DIM + be * 64 + c4);
            ls[fr][c4] = v.x; ls[fr][c4 + 1] = v.y; ls[fr][c4 + 2] = v.z; ls[fr][c4 + 3] = v.w;
        }
        __syncthreads();
        const int er = t >> 2;
        const int fc = (t & 3) * 16;
        f16x8 o0, o1;
        #pragma unroll
        for (int j = 0; j < 8; ++j) { o0[j] = (f16)ls[fc + j][er]; o1[j] = (f16)ls[fc + 8 + j][er]; }
        f16* dst = W1t + (size_t)(be * 64 + er) * F_DIM + bf * 64 + fc;
        *reinterpret_cast<f16x8*>(dst)     = o0;
        *reinterpret_cast<f16x8*>(dst + 8) = o1;
    } else if (b < 3072) {
        // Wo f32 -> f16
        size_t i = ((size_t)(b - 1024) * 256 + threadIdx.x) * 8;
        float4 v0 = *reinterpret_cast<const float4*>(wo + i);
        float4 v1 = *reinterpret_cast<const float4*>(wo + i + 4);
        *reinterpret_cast<f16x8*>(woh + i) = cvt8(v0, v1);
    } else {
        // W2 [4096][16] f32 -> w2p [4096][32] f16 (zero-padded)
        int t = (b - 3072) * 256 + threadIdx.x;
        size_t i = (size_t)t * 8;
        int col = (int)(i & 31);
        f16x8 o;
        if (col < NQ) {
            int row = (int)(i >> 5);
            float4 v0 = *reinterpret_cast<const float4*>(W2 + (size_t)row * NQ + col);
            float4 v1 = *reinterpret_cast<const float4*>(W2 + (size_t)row * NQ + col + 4);
            o = cvt8(v0, v1);
        } else {
            for (int k = 0; k < 8; ++k) o[k] = (f16)0.f;
        }
        *reinterpret_cast<f16x8*>(w2p + i) = o;
    }
}

// ---------------- tg: pT[kc][16][1024] f32 partials of T = Wq @ W1 ----------------
__global__ __launch_bounds__(256) void tg_kernel(
    const float* __restrict__ Wq, const f16* __restrict__ W1t,
    float* __restrict__ pT)
{
    const int w = threadIdx.x >> 6, lane = threadIdx.x & 63;
    const int fr = lane & 15, fq = lane >> 4;
    const int kc = blockIdx.x & 15;
    const int et = blockIdx.x >> 4;
    const int e0 = et * 128 + w * 32;
    const int kbase = kc * 256;

    f32x4 acc[2] = {};
    #pragma unroll
    for (int s = 0; s < 8; ++s) {
        int k = kbase + s * 32 + fq * 8;
        float4 a0 = *reinterpret_cast<const float4*>(Wq + (size_t)fr * F_DIM + k);
        float4 a1 = *reinterpret_cast<const float4*>(Wq + (size_t)fr * F_DIM + k + 4);
        f16x8 af = cvt8(a0, a1);
        #pragma unroll
        for (int n = 0; n < 2; ++n) {
            f16x8 bf = *reinterpret_cast<const f16x8*>(W1t + (size_t)(e0 + n * 16 + fr) * F_DIM + k);
            acc[n] = __builtin_amdgcn_mfma_f32_16x16x32_f16(af, bf, acc[n], 0, 0, 0);
        }
    }
    #pragma unroll
    for (int n = 0; n < 2; ++n)
        #pragma unroll
        for (int j = 0; j < 4; ++j)
            pT[(size_t)kc * (16 * E_DIM) + (size_t)(fq * 4 + j) * E_DIM + e0 + n * 16 + fr] = acc[n][j];
}

// ---------------- treduce: Th[16][1024] f16 = sum_kc pT ----------------
__global__ __launch_bounds__(256) void treduce_kernel(
    const float* __restrict__ pT, f16* __restrict__ Th)
{
    int idx = blockIdx.x * 256 + threadIdx.x;
    float s = 0.f;
    #pragma unroll
    for (int kc = 0; kc < 16; ++kc) s += pT[(size_t)kc * (16 * E_DIM) + idx];
    Th[idx] = (f16)s;
}

// ---------------- qx: pq2[kc][8192][16] f32 partials of q = x @ Th^T ----------------
__global__ __launch_bounds__(256) void qx_kernel(
    const float* __restrict__ x, const f16* __restrict__ Th,
    float* __restrict__ pq2)
{
    __shared__ __align__(16) f16 ths[16 * 512];
    const int tid = threadIdx.x, w = tid >> 6, lane = tid & 63;
    const int fr = lane & 15, fq = lane >> 4;
    const int kc = blockIdx.x & 1;
    const int m0 = (blockIdx.x >> 1) * 64;

    #pragma unroll
    for (int i = 0; i < 4; ++i) {
        int tau = i * 256 + tid;
        int q   = tau >> 6;
        int kb  = tau & 63;
        f16x8 v = *reinterpret_cast<const f16x8*>(Th + (size_t)q * E_DIM + kc * 512 + kb * 8);
        int boff = (q * 1024 + kb * 16) ^ ((q & 7) << 4);
        *reinterpret_cast<f16x8*>((char*)ths + boff) = v;
    }
    __syncthreads();

    const int row = m0 + w * 16 + fr;
    const float* xa = x + (size_t)row * E_DIM + kc * 512;
    f32x4 acc = {};
    #pragma unroll
    for (int s = 0; s < 16; ++s) {
        int ko = s * 32 + fq * 8;
        float4 a0 = *reinterpret_cast<const float4*>(xa + ko);
        float4 a1 = *reinterpret_cast<const float4*>(xa + ko + 4);
        f16x8 af = cvt8(a0, a1);
        int boff = (fr * 1024 + ko * 2) ^ ((fr & 7) << 4);
        f16x8 bf = *reinterpret_cast<const f16x8*>((char*)ths + boff);
        acc = __builtin_amdgcn_mfma_f32_16x16x32_f16(af, bf, acc, 0, 0, 0);
    }
    #pragma unroll
    for (int j = 0; j < 4; ++j)
        pq2[(size_t)kc * (M_TOT * NQ) + (size_t)(m0 + w * 16 + fq * 4 + j) * NQ + fr] = acc[j];
}

// ---------------- qfinal: qmp[8192][32] = cos(sum + theta), zero-pad 16..31 ----------------
__global__ __launch_bounds__(256) void qfinal_kernel(
    const float* __restrict__ pq2, const float* __restrict__ theta,
    f16* __restrict__ qmp)
{
    int t = blockIdx.x * 256 + threadIdx.x;
    int row = t >> 4, q = t & 15;
    float s = pq2[t] + pq2[(size_t)M_TOT * NQ + t];
    float v = cosf(s + theta[q]);
    qmp[(size_t)row * 32 + q]      = (f16)v;
    qmp[(size_t)row * 32 + 16 + q] = (f16)0.f;
}

__device__ __forceinline__ void gload_lds16(const f16* g, f16* l) {
    __builtin_amdgcn_global_load_lds(
        (const __attribute__((address_space(1))) void*)(g),
        (__attribute__((address_space(3))) void*)(l), 16, 0, 0);
}

// ================= fused GEMM: out = relu(qm @ W2^T) @ Wo^T, 256x256 8-phase =================
// A-tiles (h2) PRODUCED in-kernel: mini-MFMA of w2 K-slice (regs) x q-fragments
// (PERSISTENT REGISTERS, loaded once from global), relu+cvt, ds_write into the
// swizzled A-layout. LDS (f16 units): buf b in [b*32768,+32768) = { A[b] @ +0,
// B[b] @ +16384 }. Total 65536 f16 = 131072 B.
__global__ __launch_bounds__(512, 2)
void gemm4f(const f16* __restrict__ qmp, const f16* __restrict__ w2p,
            const f16* __restrict__ Wo, f16* __restrict__ P0, f16* __restrict__ P1)
{
    extern __shared__ __align__(16) f16 smem[];
    const int tid  = threadIdx.x;
    const int w    = tid >> 6;
    const int lane = tid & 63;

    const int nwg = gridDim.x;              // 256
    const int bid = blockIdx.x;
    const int cpx = nwg >> 3;
    int swz = (bid & 7) * cpx + (bid >> 3);
    const int per = nwg >> 1;               // 128
    const int split = swz / per;
    const int r = swz % per;
    const int by = r >> 2, bx = r & 3;      // gx = 4
    const int m0 = by * 256, n0 = bx * 256;

    const int wr = w >> 2, wc = w & 3;
    const int fr = lane & 15, fq = lane >> 4;
    const int K = 2048;                     // per split

    const f16* Bb  = Wo + (size_t)split * K;
    const f16* w2g = w2p + (size_t)split * K * 32;
    f16* Pout = split ? P1 : P0;

    // ---- persistent q fragments: rows (w*32+fr) and (+16) of qm tile ----
    const int r0w = w * 32 + fr;
    f16x8 qreg0 = *reinterpret_cast<const f16x8*>(qmp + (size_t)(m0 + r0w) * 32 + fq * 8);
    f16x8 qreg1 = *reinterpret_cast<const f16x8*>(qmp + (size_t)(m0 + r0w + 16) * 32 + fq * 8);

    // ---- B staging ----
    const int rl   = w * 8 + (lane >> 3);
    const int scol = (((lane & 7) ^ (rl & 7)) * 8);
    const f16* gB = Bb + (size_t)(n0 + rl) * F_DIM + scol;
    f16* lB = smem + 16384 + w * 512;       // B[b] @ b*32768 + 16384 (f16 units)

#define SB(b,h,j,kt) gload_lds16(gB + (size_t)((h)*128 + (j)*64) * F_DIM + (kt), lB + (b)*32768 + (h)*8192 + (j)*4096)
#define SBH(b,h,kt) do { SB(b,h,0,kt); SB(b,h,1,kt); } while(0)

    // ---- w2 fragment register loads (A-operand of mini-GEMM) ----
    f16x8 w2a[4], w2b[4];
#define LOADW2(R, kt) do { _Pragma("unroll") \
    for (int ft = 0; ft < 4; ++ft) \
        R[ft] = *reinterpret_cast<const f16x8*>(w2g + (size_t)((kt) + ft*16 + fr) * 32 + fq * 8); } while(0)

    // ---- produce A[bdst] = relu(qm @ w2[kt]^T) in swizzled layout (all-register inputs) ----
#define PRODUCE(bdst, W2R) do {                                                   \
    f32x4 z_ = {0.f, 0.f, 0.f, 0.f};                                              \
    _Pragma("unroll") for (int ft = 0; ft < 4; ++ft) {                            \
        f32x4 c0_ = __builtin_amdgcn_mfma_f32_16x16x32_f16(W2R[ft], qreg0, z_, 0, 0, 0); \
        f32x4 c1_ = __builtin_amdgcn_mfma_f32_16x16x32_f16(W2R[ft], qreg1, z_, 0, 0, 0); \
        f16x4 h0_, h1_;                                                           \
        _Pragma("unroll") for (int jj = 0; jj < 4; ++jj) {                        \
            h0_[jj] = (f16)fmaxf(c0_[jj], 0.f); h1_[jj] = (f16)fmaxf(c1_[jj], 0.f); } \
        const int sl_ = (2 * ft + (fq >> 1)) ^ (fr & 7);                          \
        *reinterpret_cast<f16x4*>(smem + (bdst)*32768 + (r0w)*64      + sl_*8 + ((fq & 1) << 2)) = h0_; \
        *reinterpret_cast<f16x4*>(smem + (bdst)*32768 + (r0w+16)*64   + sl_*8 + ((fq & 1) << 2)) = h1_; \
    } } while(0)

    // ---- main fragment-read bases ----
    const int xm  = fr & 7;
    const int so0 = ((0 + fq) ^ xm) * 8;
    const int so1 = ((4 + fq) ^ xm) * 8;
    const int aro = (wr * 128 + fr) * 64;
    const int bro = (wc * 64  + fr) * 64;

#define AF(b,m,ks) (*reinterpret_cast<const f16x8*>(smem + (b)*32768 + aro + (m)*1024 + so##ks))
#define BF(b,n,ks) (*reinterpret_cast<const f16x8*>(smem + (b)*32768 + 16384 + bro + (n)*1024 + so##ks))

    f32x4 acc[8][4] = {};
    f16x8 bf[4][2];

#define PHASE(b, p, STAGES, W4) do {                                              \
    f16x8 a00 = AF(b, 2*(p),   0), a01 = AF(b, 2*(p),   1);                       \
    f16x8 a10 = AF(b, 2*(p)+1, 0), a11 = AF(b, 2*(p)+1, 1);                       \
    if ((p) == 0) { _Pragma("unroll")                                             \
        for (int n = 0; n < 4; ++n) { bf[n][0] = BF(b,n,0); bf[n][1] = BF(b,n,1); } } \
    STAGES;                                                                       \
    BARRIER();                                                                    \
    __builtin_amdgcn_s_setprio(1);                                                \
    _Pragma("unroll") for (int n = 0; n < 4; ++n) {                               \
        acc[2*(p)  ][n] = __builtin_amdgcn_mfma_f32_16x16x32_f16(a00, bf[n][0], acc[2*(p)  ][n], 0,0,0); \
        acc[2*(p)+1][n] = __builtin_amdgcn_mfma_f32_16x16x32_f16(a10, bf[n][0], acc[2*(p)+1][n], 0,0,0); } \
    _Pragma("unroll") for (int n = 0; n < 4; ++n) {                               \
        acc[2*(p)  ][n] = __builtin_amdgcn_mfma_f32_16x16x32_f16(a01, bf[n][1], acc[2*(p)  ][n], 0,0,0); \
        acc[2*(p)+1][n] = __builtin_amdgcn_mfma_f32_16x16x32_f16(a11, bf[n][1], acc[2*(p)+1][n], 0,0,0); } \
    __builtin_amdgcn_s_setprio(0);                                                \
    if (W4) { WAITV(8); WAITLGKM(); }                                             \
    BARRIER(); } while(0)

    const int NT = K >> 6;      // 32
    const int NI = NT >> 1;     // 16

    // prologue: q-frags + w2[k0],w2[k1] -> regs; B0<-k0, B1<-k1; produce A[0]
    LOADW2(w2b, 0);
    LOADW2(w2a, 64);
    SBH(0,0,0);  SBH(0,1,0);
    SBH(1,0,64); SBH(1,1,64);
    WAITV(0);
    BARRIER();
    PRODUCE(0, w2b);
    WAITLGKM();
    BARRIER();

    for (int i = 0; i < NI; ++i) {
        const int k1 = (2*i+1) << 6;
        int t2 = 2*i+2; if (t2 > NT-1) t2 = NT-1;
        int t3 = 2*i+3; if (t3 > NT-1) t3 = NT-1;
        const int k2 = t2 << 6, k3 = t3 << 6;
        PHASE(0, 0, PRODUCE(1, w2a),            0);   // P1: produce A[1]<-k1
        PHASE(0, 1, LOADW2(w2b, k2); SBH(0,0,k2), 0); // P2
        PHASE(0, 2, SBH(0,1,k2),                0);   // P3
        PHASE(0, 3, ,                           1);   // P4: vmcnt(8)+lgkm(0)
        PHASE(1, 0, PRODUCE(0, w2b),            0);   // P5: produce A[0]<-k2
        PHASE(1, 1, LOADW2(w2a, k3); SBH(1,0,k3), 0); // P6
        PHASE(1, 2, SBH(1,1,k3),                0);   // P7
        PHASE(1, 3, ,                           1);   // P8: vmcnt(8)+lgkm(0)
    }
    WAITV(0);

    #pragma unroll
    for (int m = 0; m < 8; ++m) {
        #pragma unroll
        for (int n = 0; n < 4; ++n) {
            #pragma unroll
            for (int j = 0; j < 4; ++j) {
                int row = m0 + wr * 128 + m * 16 + fq * 4 + j;
                int col = n0 + wc * 64  + n * 16 + fr;
                Pout[(size_t)row * E_DIM + col] = (f16)acc[m][n][j];
            }
        }
    }
#undef SB
#undef SBH
#undef LOADW2
#undef PRODUCE
#undef AF
#undef BF
#undef PHASE
}

// ---------------- out = (float)p0 + (float)p1 ----------------
__global__ __launch_bounds__(256) void out_reduce2_kernel(
    float* __restrict__ out, const f16* __restrict__ p0, const f16* __restrict__ p1)
{
    size_t i = ((size_t)blockIdx.x * 256 + threadIdx.x) * 8;
    f16x8 a = *reinterpret_cast<const f16x8*>(p0 + i);
    f16x8 b = *reinterpret_cast<const f16x8*>(p1 + i);
    float4 v0, v1;
    v0.x = (float)a[0] + (float)b[0]; v0.y = (float)a[1] + (float)b[1];
    v0.z = (float)a[2] + (float)b[2]; v0.w = (float)a[3] + (float)b[3];
    v1.x = (float)a[4] + (float)b[4]; v1.y = (float)a[5] + (float)b[5];
    v1.z = (float)a[6] + (float)b[6]; v1.w = (float)a[7] + (float)b[7];
    *reinterpret_cast<float4*>(out + i)     = v0;
    *reinterpret_cast<float4*>(out + i + 4) = v1;
}

extern "C" void kernel_launch(void* const* d_in, const int* in_sizes, int n_in,
                              void* d_out, int out_size, void* d_ws, size_t ws_size,
                              hipStream_t stream) {
    const float* x  = (const float*)d_in[0];
    const float* W1 = (const float*)d_in[1];
    const float* Wq = (const float*)d_in[2];
    const float* th = (const float*)d_in[3];
    const float* W2 = (const float*)d_in[4];
    const float* Wo = (const float*)d_in[5];
    float* out = (float*)d_out;

    char* base = (char*)d_ws;
    float* pT  = (float*)base;                            // 1 MB   (dead after treduce)
    f16*   Th  = (f16*)(base + (1 << 20));                // 32 KB  (dead after qx)
    float* pq2 = (float*)(base + (1 << 20) + (1 << 16));  // 1 MB   (dead after qfinal)
    f16*   w1t = (f16*)(base + 16777216);                 // 8.4 MB
    f16*   woh = w1t + (size_t)E_DIM * F_DIM;             // 8.4 MB
    f16*   w2p = woh + (size_t)E_DIM * F_DIM;             // 0.26 MB
    f16*   qmp = w2p + (size_t)F_DIM * 32;                // 0.52 MB
    f16*   p0  = qmp + (size_t)M_TOT * 32;                // 16.8 MB
    f16*   p1  = p0  + (size_t)M_TOT * E_DIM;             // 16.8 MB

    static bool attr_done = false;
    if (!attr_done) {
        hipFuncSetAttribute((const void*)&gemm4f,
                            hipFuncAttributeMaxDynamicSharedMemorySize, 131072);
        attr_done = true;
    }

    // 1) prep (merged): W1 transpose-cast | Wo cast | W2 pad
    prep_kernel<<<3136, 256, 0, stream>>>(W1, w1t, Wo, woh, W2, w2p);
    // 2) T = Wq @ W1 -> Th f16 [16][1024]
    tg_kernel<<<128, 256, 0, stream>>>(Wq, w1t, pT);
    treduce_kernel<<<64, 256, 0, stream>>>(pT, Th);
    // 3) q = x @ Th^T, cos(q+theta) -> qmp [8192][32]
    qx_kernel<<<256, 256, 0, stream>>>(x, Th, pq2);
    qfinal_kernel<<<512, 256, 0, stream>>>(pq2, th, qmp);
    // 4) fused: out-partials = relu(qmp @ w2p^T) @ Wo^T, split-K=2, f16 partials
    gemm4f<<<256, 512, 131072, stream>>>(qmp, w2p, woh, p0, p1);
    // 5) out = p0 + p1
    out_reduce2_kernel<<<4096, 256, 0, stream>>>(out, p0, p1);
}